// Round 12
// baseline (1203.548 us; speedup 1.0000x reference)
//
#include <hip/hip_runtime.h>
#include <hip/hip_bf16.h>
#include <math.h>

#define DEVINL __device__ __forceinline__

typedef __attribute__((ext_vector_type(2))) float  f32x2;
typedef __attribute__((ext_vector_type(4))) float  f32x4;
typedef __attribute__((ext_vector_type(8))) __bf16 bf16x8;
typedef __attribute__((ext_vector_type(8))) unsigned short ushort8;

DEVINL float b2f(unsigned short u) {
    union { unsigned int i; float f; } v; v.i = ((unsigned int)u) << 16; return v.f;
}
DEVINL unsigned short f2b(float f) {
    union { float f; unsigned int i; } v; v.f = f;
    unsigned int u = v.i;
    unsigned int r = (u + 0x7fffu + ((u >> 16) & 1u)) >> 16;
    return (unsigned short)r;
}
DEVINL float gelu_exact(float x) {
    return 0.5f * x * (1.0f + erff(x * 0.70710678118654752440f));
}

// VOP3P packed fp32 (CDNA2+): 2 FLOPs per instruction on register pairs.
DEVINL f32x2 pk_fma(f32x2 a, f32x2 b, f32x2 c) {
    f32x2 d; asm("v_pk_fma_f32 %0, %1, %2, %3" : "=v"(d) : "v"(a), "v"(b), "v"(c)); return d;
}
DEVINL f32x2 pk_add(f32x2 a, f32x2 b) {
    f32x2 d; asm("v_pk_add_f32 %0, %1, %2" : "=v"(d) : "v"(a), "v"(b)); return d;
}
DEVINL f32x2 pk_mul(f32x2 a, f32x2 b) {
    f32x2 d; asm("v_pk_mul_f32 %0, %1, %2" : "=v"(d) : "v"(a), "v"(b)); return d;
}

// Barrier that drains ONLY LDS (lgkmcnt).
DEVINL void bar_lgkm() {
    asm volatile("s_waitcnt lgkmcnt(0)" ::: "memory");
    __builtin_amdgcn_s_barrier();
    __builtin_amdgcn_sched_barrier(0);
}

// LDS XOR swizzle (T2): permute 8-element groups within a 64-elem row by row&7.
DEVINL int swz(int off) { return off ^ (((off >> 6) & 7) << 3); }

// Direct global->LDS async copy, 16B per lane (linear LDS dest).
DEVINL void gload16(const unsigned short* g, unsigned short* l) {
    __builtin_amdgcn_global_load_lds(
        (const __attribute__((address_space(1))) unsigned int*)g,
        (__attribute__((address_space(3))) unsigned int*)l, 16, 0, 0);
}

// DPP-based wave64 sum: result valid in lane 63 of each wave.
template <int CTRL>
DEVINL float dpp_add(float x) {
    int xi = __builtin_bit_cast(int, x);
    int yi = __builtin_amdgcn_update_dpp(0, xi, CTRL, 0xf, 0xf, true);
    return x + __builtin_bit_cast(float, yi);
}
DEVINL float wave_sum63(float x) {
    x = dpp_add<0x111>(x);
    x = dpp_add<0x112>(x);
    x = dpp_add<0x114>(x);
    x = dpp_add<0x118>(x);
    x = dpp_add<0x142>(x);
    x = dpp_add<0x143>(x);
    return x;
}

// ---------------------------------------------------------------------------
// conv1 (Cin=8 -> 256, k=3, pad=1) + ReLU, output bf16.
__global__ __launch_bounds__(256) void conv1_kernel(
    const float* __restrict__ x, const float* __restrict__ w,
    const float* __restrict__ bias, unsigned short* __restrict__ h1)
{
    __shared__ float xs[52 * 8];
    int b = blockIdx.x >> 3, tile = blockIdx.x & 7;
    int p0 = tile * 50;
    int t = threadIdx.x;
    for (int i = t; i < 416; i += 256) {
        int p = i >> 3, c = i & 7;
        int lp = p0 + p - 1;
        xs[i] = (lp >= 0 && lp < 400) ? x[((size_t)b * 400 + lp) * 8 + c] : 0.0f;
    }
    float wr[24];
    const float4* wp = (const float4*)(w + t * 24);
#pragma unroll
    for (int i = 0; i < 6; ++i) {
        float4 v4 = wp[i];
        wr[i * 4] = v4.x; wr[i * 4 + 1] = v4.y; wr[i * 4 + 2] = v4.z; wr[i * 4 + 3] = v4.w;
    }
    float bs = bias[t];
    __syncthreads();
#pragma unroll 2
    for (int p = 0; p < 50; ++p) {
        float acc = bs;
#pragma unroll
        for (int dt = 0; dt < 3; ++dt)
#pragma unroll
            for (int c = 0; c < 8; ++c)
                acc += xs[(p + dt) * 8 + c] * wr[c * 3 + dt];
        h1[((size_t)b * 400 + p0 + p) * 256 + t] = f2b(fmaxf(acc, 0.0f));
    }
}

// conv2 weight reorder (o, ci, t) -> w2r[o, t*256+ci] bf16
__global__ void reorder_w2_kernel(const float* __restrict__ w, unsigned short* __restrict__ out)
{
    int idx = blockIdx.x * 256 + threadIdx.x;
    if (idx >= 256 * 768) return;
    int o = idx / 768, r = idx % 768;
    int tpos = r / 256, ci = r % 256;
    out[idx] = f2b(w[o * 768 + ci * 3 + tpos]);
}

__global__ void castw_kernel(const float* __restrict__ in, unsigned short* __restrict__ out, int n)
{
    int i = blockIdx.x * 256 + threadIdx.x;
    if (i < n) out[i] = f2b(in[i]);
}

// ---------------------------------------------------------------------------
// LayerNorm over dm=256 per row, fp32 in -> bf16 out. 4 rows/block (1/wave).
__global__ __launch_bounds__(256) void ln_kernel(
    const float* __restrict__ h, const float* __restrict__ g,
    const float* __restrict__ bta, unsigned short* __restrict__ out)
{
    int w = threadIdx.x >> 6, l = threadIdx.x & 63;
    int row = blockIdx.x * 4 + w;
    const float* p = h + (size_t)row * 256 + l * 4;
    float4 v = *(const float4*)p;
    float s  = v.x + v.y + v.z + v.w;
    float s2 = v.x * v.x + v.y * v.y + v.z * v.z + v.w * v.w;
#pragma unroll
    for (int m = 1; m < 64; m <<= 1) { s += __shfl_xor(s, m); s2 += __shfl_xor(s2, m); }
    float mu = s * (1.0f / 256.0f);
    float var = s2 * (1.0f / 256.0f) - mu * mu;
    float rs = rsqrtf(var + 1e-5f);
    float4 gg = *(const float4*)(g + l * 4);
    float4 bb = *(const float4*)(bta + l * 4);
    ushort4 o;
    o.x = f2b((v.x - mu) * rs * gg.x + bb.x);
    o.y = f2b((v.y - mu) * rs * gg.y + bb.y);
    o.z = f2b((v.z - mu) * rs * gg.z + bb.z);
    o.w = f2b((v.w - mu) * rs * gg.w + bb.w);
    *(ushort4*)(out + (size_t)row * 256 + l * 4) = o;
}

// ---------------------------------------------------------------------------
// bf16 GEMM, 128x256 tile (BM=128, BN=256), 256 threads / 4 waves,
// wave-tile 64x128, acc[4][8]. Staging: global_load_lds + pre-swizzled source.
// EPI 3: +bias+res fp32 out.  EPI 4: fused inproj split epilogue (ldc=512).
template <int EPI>
__global__ __launch_bounds__(256) void gemm_bt2(
    const unsigned short* __restrict__ A, const unsigned short* __restrict__ Bt,
    const float* __restrict__ bias, const float* __restrict__ res,
    void* __restrict__ Cout, int nbn, int K, int lda, int ldc)
{
    __shared__ unsigned short As[128 * 64];
    __shared__ unsigned short Bs[256 * 64];
    int bm = blockIdx.x / nbn, bn = blockIdx.x % nbn;
    int t = threadIdx.x, l = t & 63, w = t >> 6;
    int wm = w & 1, wn = w >> 1;
    int srow = t >> 3;                         // 0..31 per round
    int scol = 8 * ((t & 7) ^ ((t >> 3) & 7)); // pre-swizzled source column
    f32x4 acc[4][8] = {};
    const int ktn = K >> 6;
    for (int kt = 0; kt < ktn; ++kt) {
#pragma unroll
        for (int i = 0; i < 4; ++i) {
            int row = i * 32 + srow;
            gload16(A + (size_t)(bm * 128 + row) * lda + kt * 64 + scol,
                    As + (i * 256 + w * 64) * 8);
        }
#pragma unroll
        for (int j = 0; j < 8; ++j) {
            int row = j * 32 + srow;
            gload16(Bt + (size_t)(bn * 256 + row) * K + kt * 64 + scol,
                    Bs + (j * 256 + w * 64) * 8);
        }
        __syncthreads();
#pragma unroll
        for (int kk = 0; kk < 2; ++kk) {
            bf16x8 af[4], bfr[8];
#pragma unroll
            for (int i = 0; i < 4; ++i)
                af[i]  = *(const bf16x8*)(As + swz((wm * 64 + i * 16 + (l & 15)) * 64 + kk * 32 + (l >> 4) * 8));
#pragma unroll
            for (int j = 0; j < 8; ++j)
                bfr[j] = *(const bf16x8*)(Bs + swz((wn * 128 + j * 16 + (l & 15)) * 64 + kk * 32 + (l >> 4) * 8));
#pragma unroll
            for (int i = 0; i < 4; ++i)
#pragma unroll
                for (int j = 0; j < 8; ++j)
                    acc[i][j] = __builtin_amdgcn_mfma_f32_16x16x32_bf16(af[i], bfr[j], acc[i][j], 0, 0, 0);
        }
        __syncthreads();
    }
    int r0 = bm * 128 + wm * 64 + (l >> 4) * 4;
    int c0 = bn * 256 + wn * 128 + (l & 15);
#pragma unroll
    for (int i = 0; i < 4; ++i) {
#pragma unroll
        for (int j = 0; j < 8; ++j) {
            int col = c0 + j * 16;
            float bb = bias[col];
#pragma unroll
            for (int q = 0; q < 4; ++q) {
                int row = r0 + i * 16 + q;
                float v = acc[i][j][q] + bb;
                if (EPI == 3) {
                    size_t idx = (size_t)row * ldc + col;
                    ((float*)Cout)[idx] = v + res[idx];
                } else {    // EPI 4: fused inproj split epilogue
                    if (col < 512)
                        ((unsigned short*)Cout)[(size_t)row * 512 + col] = f2b(v);
                    else
                        ((unsigned short*)res)[(size_t)row * 512 + (col - 512)] = f2b(gelu_exact(v));
                }
            }
        }
    }
}

// ---------------------------------------------------------------------------
// conv2 as GEMM with FUSED im2col staging, 128x256 tile (N=256 in one block).
// Reg-staged (needs boundary zeros). ReLU epilogue, fp32 out. 400 blocks.
__global__ __launch_bounds__(256) void gemm_conv2(
    const unsigned short* __restrict__ h1, const unsigned short* __restrict__ Bt,
    const float* __restrict__ bias, float* __restrict__ Cout)
{
    __shared__ unsigned short As[128 * 64];
    __shared__ unsigned short Bs[256 * 64];
    int bm = blockIdx.x;
    int t = threadIdx.x, l = t & 63, w = t >> 6;
    int wm = w & 1, wn = w >> 1;
    f32x4 acc[4][8] = {};
    for (int kt = 0; kt < 12; ++kt) {
        int tpos = kt >> 2;
        int cbase = (kt & 3) * 64;
#pragma unroll
        for (int i = 0; i < 4; ++i) {
            int off = (i * 256 + t) * 8;
            int row = off >> 6, col = off & 63;
            int m = bm * 128 + row;
            int b = m / 400, ll = m % 400;
            int lp = ll + tpos - 1;
            ushort8 va = (ushort8)0;
            if (lp >= 0 && lp < 400)
                va = *(const ushort8*)(h1 + ((size_t)(b * 400 + lp) * 256 + cbase + col));
            *(ushort8*)(As + swz(off)) = va;
        }
#pragma unroll
        for (int j = 0; j < 8; ++j) {
            int off = (j * 256 + t) * 8;
            int row = off >> 6, col = off & 63;
            ushort8 vb = *(const ushort8*)(Bt + (size_t)row * 768 + kt * 64 + col);
            *(ushort8*)(Bs + swz(off)) = vb;
        }
        __syncthreads();
#pragma unroll
        for (int kk = 0; kk < 2; ++kk) {
            bf16x8 af[4], bfr[8];
#pragma unroll
            for (int i = 0; i < 4; ++i)
                af[i]  = *(const bf16x8*)(As + swz((wm * 64 + i * 16 + (l & 15)) * 64 + kk * 32 + (l >> 4) * 8));
#pragma unroll
            for (int j = 0; j < 8; ++j)
                bfr[j] = *(const bf16x8*)(Bs + swz((wn * 128 + j * 16 + (l & 15)) * 64 + kk * 32 + (l >> 4) * 8));
#pragma unroll
            for (int i = 0; i < 4; ++i)
#pragma unroll
                for (int j = 0; j < 8; ++j)
                    acc[i][j] = __builtin_amdgcn_mfma_f32_16x16x32_bf16(af[i], bfr[j], acc[i][j], 0, 0, 0);
        }
        __syncthreads();
    }
    int r0 = bm * 128 + wm * 64 + (l >> 4) * 4;
    int c0 = wn * 128 + (l & 15);
#pragma unroll
    for (int i = 0; i < 4; ++i)
#pragma unroll
        for (int j = 0; j < 8; ++j) {
            int col = c0 + j * 16;
            float bb = bias[col];
#pragma unroll
            for (int q = 0; q < 4; ++q) {
                int row = r0 + i * 16 + q;
                Cout[(size_t)row * 256 + col] = fmaxf(acc[i][j][q] + bb, 0.0f);
            }
        }
}

// ---------------------------------------------------------------------------
// depthwise conv (k=3, pad=1) + GELU; bf16 in/out; register-sliding window.
__global__ __launch_bounds__(256) void dwconv_kernel(
    const unsigned short* __restrict__ xp, const float* __restrict__ w,
    const float* __restrict__ bias, unsigned short* __restrict__ out)
{
    int b = blockIdx.x >> 3, tile = blockIdx.x & 7;
    int p0 = tile * 50;
    int t = threadIdx.x;
    int c = t * 2;
    float w00 = w[c * 3], w01 = w[c * 3 + 1], w02 = w[c * 3 + 2];
    float w10 = w[c * 3 + 3], w11 = w[c * 3 + 4], w12 = w[c * 3 + 5];
    float b0 = bias[c], b1 = bias[c + 1];
    const size_t rowb = (size_t)b * 400;
    int l = p0;
    unsigned int r0 = (l - 1 >= 0) ? *(const unsigned int*)(xp + (rowb + l - 1) * 512 + c) : 0u;
    unsigned int r1 = *(const unsigned int*)(xp + (rowb + l) * 512 + c);
    for (int q = 0; q < 50; ++q, ++l) {
        unsigned int r2 = (l + 1 < 400) ? *(const unsigned int*)(xp + (rowb + l + 1) * 512 + c) : 0u;
        float a0 = b0 + b2f((unsigned short)(r0 & 0xffff)) * w00
                      + b2f((unsigned short)(r1 & 0xffff)) * w01
                      + b2f((unsigned short)(r2 & 0xffff)) * w02;
        float a1 = b1 + b2f((unsigned short)(r0 >> 16)) * w10
                      + b2f((unsigned short)(r1 >> 16)) * w11
                      + b2f((unsigned short)(r2 >> 16)) * w12;
        unsigned int o = (unsigned int)f2b(gelu_exact(a0)) | ((unsigned int)f2b(gelu_exact(a1)) << 16);
        *(unsigned int*)(out + (rowb + l) * 512 + c) = o;
        r0 = r1; r1 = r2;
    }
}

// ---------------------------------------------------------------------------
// xproj as MFMA GEMM: BC(M x 32) = tanh(xcv(M x 512) @ W^T(32x512) + b).
__global__ __launch_bounds__(256) void xproj_mfma(
    const unsigned short* __restrict__ xc, const unsigned short* __restrict__ w,
    const float* __restrict__ bias, float* __restrict__ BC)
{
    __shared__ unsigned short As[128 * 64];
    __shared__ unsigned short Bs[32 * 64];
    int bm = blockIdx.x;
    int t = threadIdx.x, l = t & 63, wv = t >> 6;
    f32x4 acc[2][2] = {};
    for (int kt = 0; kt < 8; ++kt) {
#pragma unroll
        for (int i = 0; i < 4; ++i) {
            int off = (i * 256 + t) * 8;
            int row = off >> 6, col = off & 63;
            ushort8 va = *(const ushort8*)(xc + (size_t)(bm * 128 + row) * 512 + kt * 64 + col);
            *(ushort8*)(As + swz(off)) = va;
        }
        {
            int off = t * 8;
            int row = off >> 6, col = off & 63;
            ushort8 vb = *(const ushort8*)(w + (size_t)row * 512 + kt * 64 + col);
            *(ushort8*)(Bs + swz(off)) = vb;
        }
        __syncthreads();
#pragma unroll
        for (int kk = 0; kk < 2; ++kk) {
            bf16x8 af[2], bfr[2];
#pragma unroll
            for (int i = 0; i < 2; ++i) {
                af[i]  = *(const bf16x8*)(As + swz((wv * 32 + i * 16 + (l & 15)) * 64 + kk * 32 + (l >> 4) * 8));
                bfr[i] = *(const bf16x8*)(Bs + swz((i * 16 + (l & 15)) * 64 + kk * 32 + (l >> 4) * 8));
            }
#pragma unroll
            for (int i = 0; i < 2; ++i)
#pragma unroll
                for (int j = 0; j < 2; ++j)
                    acc[i][j] = __builtin_amdgcn_mfma_f32_16x16x32_bf16(af[i], bfr[j], acc[i][j], 0, 0, 0);
        }
        __syncthreads();
    }
    int r0 = bm * 128 + wv * 32 + (l >> 4) * 4;
    int c0 = l & 15;
#pragma unroll
    for (int i = 0; i < 2; ++i)
#pragma unroll
        for (int j = 0; j < 2; ++j) {
            int col = c0 + j * 16;
            float bb = bias[col];
#pragma unroll
            for (int q = 0; q < 4; ++q) {
                int row = r0 + i * 16 + q;
                BC[(size_t)row * 32 + col] = tanhf(acc[i][j][q] + bb);
            }
        }
}

// ---------------------------------------------------------------------------
// Sequential SSM scan. 256 threads (4 waves), 2 channels/thread (32 states).
// 50 chunks x 8 unrolled phases, register-resident operands, counted-lgkmcnt
// pre-barrier prefetch. (round-11 structure, unchanged)
__global__ __launch_bounds__(256) void scan_kernel(
    const float* __restrict__ BC, const unsigned short* __restrict__ xconv,
    const unsigned short* __restrict__ gres, const float* __restrict__ Aw,
    const float* __restrict__ Dw, const float* __restrict__ sng,
    const float* __restrict__ snb, unsigned short* __restrict__ yg)
{
    __shared__ __align__(16) unsigned short lds_x[2][4096];
    __shared__ __align__(16) unsigned short lds_g[2][4096];
    __shared__ __align__(16) float lds_bc[2][256];
    __shared__ __align__(16) float lds_s1[2][4];
    __shared__ __align__(16) float lds_s2[2][4];
    int b = blockIdx.x, t = threadIdx.x;
    int d0 = t * 2;
    f32x2 st2[16], tA2[16], g2[16], bb2[16];
#pragma unroll
    for (int ch = 0; ch < 2; ++ch)
#pragma unroll
        for (int j = 0; j < 8; ++j) {
            int idx = ch * 8 + j;
            st2[idx] = (f32x2)(0.0f);
            f32x2 av = *(const f32x2*)(Aw + (d0 + ch) * 16 + j * 2);
            tA2[idx] = (f32x2){tanhf(av.x), tanhf(av.y)};
            g2[idx]  = *(const f32x2*)(sng + (d0 + ch) * 16 + j * 2);
            bb2[idx] = *(const f32x2*)(snb + (d0 + ch) * 16 + j * 2);
        }
    f32x2 Dd = *(const f32x2*)(Dw + d0);
    const size_t base = (size_t)b * 400;
    {
        size_t o = base * 512 + t * 16;
        *(ushort8*)(&lds_x[0][t * 16])     = *(const ushort8*)(xconv + o);
        *(ushort8*)(&lds_x[0][t * 16 + 8]) = *(const ushort8*)(xconv + o + 8);
        *(ushort8*)(&lds_g[0][t * 16])     = *(const ushort8*)(gres + o);
        *(ushort8*)(&lds_g[0][t * 16 + 8]) = *(const ushort8*)(gres + o + 8);
        if (t < 64) *(float4*)(&lds_bc[0][t * 4]) = *(const float4*)(BC + base * 32 + t * 4);
    }
    bar_lgkm();
    float4 bcv[8];
#pragma unroll
    for (int q = 0; q < 8; ++q) bcv[q] = *(const float4*)&lds_bc[0][q * 4];
    unsigned int cxr = *(const unsigned int*)&lds_x[0][d0];
    unsigned int cgr = *(const unsigned int*)&lds_g[0][d0];
    ushort8 xr0, xr1, gr0, gr1; float4 bc_r;
    for (int c = 0; c < 50; ++c) {
        int cur = c & 1;
        const size_t lbase = base + c * 8;
#pragma unroll
        for (int pp = 0; pp < 8; ++pp) {
            if (pp == 0 && c + 1 < 50) {
                size_t o = (lbase + 8) * 512 + t * 16;
                xr0 = *(const ushort8*)(xconv + o);
                xr1 = *(const ushort8*)(xconv + o + 8);
                gr0 = *(const ushort8*)(gres + o);
                gr1 = *(const ushort8*)(gres + o + 8);
                if (t < 64) bc_r = *(const float4*)(BC + (lbase + 8) * 32 + t * 4);
            }
            const f32x2* Bp = (const f32x2*)&bcv[0];
            const f32x2* Cp = (const f32x2*)&bcv[4];
            float x0 = b2f((unsigned short)(cxr & 0xffff)), x1 = b2f((unsigned short)(cxr >> 16));
            float ga0 = b2f((unsigned short)(cgr & 0xffff)), ga1 = b2f((unsigned short)(cgr >> 16));
            f32x2 o0A = (f32x2){x0 * Dd.x, 0.0f}, o0B = (f32x2)(0.0f);
            f32x2 o1A = (f32x2){x1 * Dd.y, 0.0f}, o1B = (f32x2)(0.0f);
#pragma unroll
            for (int j = 0; j < 8; j += 2) {
                st2[j]     = pk_add(st2[j],     Bp[j]);     o0A = pk_fma(st2[j],     Cp[j],     o0A);
                st2[j + 1] = pk_add(st2[j + 1], Bp[j + 1]); o0B = pk_fma(st2[j + 1], Cp[j + 1], o0B);
                st2[8 + j]     = pk_add(st2[8 + j],     Bp[j]);     o1A = pk_fma(st2[8 + j],     Cp[j],     o1A);
                st2[8 + j + 1] = pk_add(st2[8 + j + 1], Bp[j + 1]); o1B = pk_fma(st2[8 + j + 1], Cp[j + 1], o1B);
            }
            f32x2 o0 = pk_add(o0A, o0B), o1 = pk_add(o1A, o1B);
            unsigned int oy = (unsigned int)f2b((o0.x + o0.y) * ga0)
                            | ((unsigned int)f2b((o1.x + o1.y) * ga1) << 16);
            *(unsigned int*)(yg + (lbase + pp) * 512 + d0) = oy;
            f32x2 sA = (f32x2)(0.0f), sB = (f32x2)(0.0f), sC = (f32x2)(0.0f), sD = (f32x2)(0.0f);
            f32x2 qA = (f32x2)(0.0f), qB = (f32x2)(0.0f), qC = (f32x2)(0.0f), qD = (f32x2)(0.0f);
#pragma unroll
            for (int j = 0; j < 16; j += 4) {
                st2[j]     = pk_mul(st2[j],     tA2[j]);     sA = pk_add(sA, st2[j]);     qA = pk_fma(st2[j],     st2[j],     qA);
                st2[j + 1] = pk_mul(st2[j + 1], tA2[j + 1]); sB = pk_add(sB, st2[j + 1]); qB = pk_fma(st2[j + 1], st2[j + 1], qB);
                st2[j + 2] = pk_mul(st2[j + 2], tA2[j + 2]); sC = pk_add(sC, st2[j + 2]); qC = pk_fma(st2[j + 2], st2[j + 2], qC);
                st2[j + 3] = pk_mul(st2[j + 3], tA2[j + 3]); sD = pk_add(sD, st2[j + 3]); qD = pk_fma(st2[j + 3], st2[j + 3], qD);
            }
            f32x2 sS = pk_add(pk_add(sA, sB), pk_add(sC, sD));
            f32x2 qS = pk_add(pk_add(qA, qB), pk_add(qC, qD));
            float s1 = wave_sum63(sS.x + sS.y);
            float s2 = wave_sum63(qS.x + qS.y);
            if (pp == 6 && c + 1 < 50) {
                if (t < 64) *(float4*)(&lds_bc[cur ^ 1][t * 4]) = bc_r;
            }
            if (pp == 7 && c + 1 < 50) {
                *(ushort8*)(&lds_x[cur ^ 1][t * 16])     = xr0;
                *(ushort8*)(&lds_x[cur ^ 1][t * 16 + 8]) = xr1;
                *(ushort8*)(&lds_g[cur ^ 1][t * 16])     = gr0;
                *(ushort8*)(&lds_g[cur ^ 1][t * 16 + 8]) = gr1;
            }
            if ((t & 63) == 63) { lds_s1[pp & 1][t >> 6] = s1; lds_s2[pp & 1][t >> 6] = s2; }
            __builtin_amdgcn_sched_barrier(0);
            float4 nbc[8]; unsigned int nxr = 0, ngr = 0;
            if (pp < 7) {
#pragma unroll
                for (int q = 0; q < 8; ++q)
                    nbc[q] = *(const float4*)&lds_bc[cur][(pp + 1) * 32 + q * 4];
                nxr = *(const unsigned int*)&lds_x[cur][(pp + 1) * 512 + d0];
                ngr = *(const unsigned int*)&lds_g[cur][(pp + 1) * 512 + d0];
                __builtin_amdgcn_sched_barrier(0);
                asm volatile("s_waitcnt lgkmcnt(10)" ::: "memory");
            } else if (c + 1 < 50) {
#pragma unroll
                for (int q = 0; q < 8; ++q)
                    nbc[q] = *(const float4*)&lds_bc[cur ^ 1][q * 4];
                __builtin_amdgcn_sched_barrier(0);
                asm volatile("s_waitcnt lgkmcnt(8)" ::: "memory");
            } else {
                asm volatile("s_waitcnt lgkmcnt(0)" ::: "memory");
            }
            __builtin_amdgcn_s_barrier();
            __builtin_amdgcn_sched_barrier(0);
            float4 p0v = *(const float4*)&lds_s1[pp & 1][0];
            float4 r0v = *(const float4*)&lds_s2[pp & 1][0];
            float S1 = (p0v.x + p0v.y) + (p0v.z + p0v.w);
            float S2 = (r0v.x + r0v.y) + (r0v.z + r0v.w);
            float mu = S1 * (1.0f / 8192.0f);
            float var = S2 * (1.0f / 8192.0f) - mu * mu;
            float rs = rsqrtf(var + 1e-5f);
            f32x2 rs2 = (f32x2){rs, rs};
            f32x2 nm2 = (f32x2){-mu * rs, -mu * rs};
#pragma unroll
            for (int j = 0; j < 16; ++j) {
                f32x2 zn = pk_fma(st2[j], rs2, nm2);
                st2[j] = pk_fma(zn, g2[j], bb2[j]);
            }
            if (pp < 7) {
#pragma unroll
                for (int q = 0; q < 8; ++q) bcv[q] = nbc[q];
                cxr = nxr; cgr = ngr;
            } else if (c + 1 < 50) {
#pragma unroll
                for (int q = 0; q < 8; ++q) bcv[q] = nbc[q];
                cxr = *(const unsigned int*)&lds_x[cur ^ 1][d0];
                cgr = *(const unsigned int*)&lds_g[cur ^ 1][d0];
            }
        }
    }
}

// ---------------------------------------------------------------------------
// mean over L then FC (37 classes). 1 block per batch.
__global__ __launch_bounds__(256) void poolfc_kernel(
    const float* __restrict__ h, const float* __restrict__ fcw,
    const float* __restrict__ fcb, float* __restrict__ out)
{
    __shared__ float ps[256];
    int b = blockIdx.x, t = threadIdx.x;
    float s = 0.0f;
    for (int l = 0; l < 400; ++l) s += h[((size_t)b * 400 + l) * 256 + t];
    ps[t] = s * (1.0f / 400.0f);
    __syncthreads();
    if (t < 37) {
        float acc = fcb[t];
        for (int o = 0; o < 256; ++o) acc += ps[o] * fcw[t * 256 + o];
        out[b * 37 + t] = acc;
    }
}

// ---------------------------------------------------------------------------
extern "C" void kernel_launch(void* const* d_in, const int* in_sizes, int n_in,
                              void* d_out, int out_size, void* d_ws, size_t ws_size,
                              hipStream_t stream)
{
    const float* x         = (const float*)d_in[0];
    const float* conv1_w   = (const float*)d_in[1];
    const float* conv1_b   = (const float*)d_in[2];
    const float* conv2_w   = (const float*)d_in[3];
    const float* conv2_b   = (const float*)d_in[4];
    const float* ln_g      = (const float*)d_in[5];
    const float* ln_b      = (const float*)d_in[6];
    const float* inproj_w  = (const float*)d_in[7];
    const float* inproj_b  = (const float*)d_in[8];
    const float* dw_w      = (const float*)d_in[9];
    const float* dw_b      = (const float*)d_in[10];
    const float* xproj_w   = (const float*)d_in[11];
    const float* xproj_b   = (const float*)d_in[12];
    const float* A         = (const float*)d_in[13];
    const float* D         = (const float*)d_in[14];
    const float* sn_g      = (const float*)d_in[15];
    const float* sn_b      = (const float*)d_in[16];
    const float* outproj_w = (const float*)d_in[17];
    const float* outproj_b = (const float*)d_in[18];
    const float* fc_w      = (const float*)d_in[19];
    const float* fc_b      = (const float*)d_in[20];
    float* out = (float*)d_out;

    const int M = 51200; // B*L

    if (ws_size < 243007488u) return;
    char* ws = (char*)d_ws;
    float*          h    = (float*)(ws);
    unsigned short* hn   = (unsigned short*)(ws + 52428800);
    unsigned short* h1   = (unsigned short*)(ws + 52428800);
    unsigned short* xp_c = (unsigned short*)(ws + 78643200);
    unsigned short* yg   = (unsigned short*)(ws + 78643200);
    unsigned short* grs  = (unsigned short*)(ws + 131072000);
    unsigned short* xcv  = (unsigned short*)(ws + 183500800);
    float*          BC   = (float*)(ws + 235929600);
    unsigned short* wbuf = (unsigned short*)(ws + 242483200);

    conv1_kernel<<<128 * 8, 256, 0, stream>>>(x, conv1_w, conv1_b, h1);
    reorder_w2_kernel<<<768, 256, 0, stream>>>(conv2_w, wbuf);
    gemm_conv2<<<M / 128, 256, 0, stream>>>(h1, wbuf, conv2_b, h);

    for (int i = 0; i < 2; ++i) {
        ln_kernel<<<M / 4, 256, 0, stream>>>(h, ln_g + i * 256, ln_b + i * 256, hn);
        castw_kernel<<<1024, 256, 0, stream>>>(inproj_w + (size_t)i * 262144, wbuf, 262144);
        // fused inproj: 128x256 tile, nbn = 1024/256 = 4
        gemm_bt2<4><<<(M / 128) * 4, 256, 0, stream>>>(hn, wbuf, inproj_b + i * 1024,
                                                       (const float*)grs, xp_c, 4, 256, 256, 512);
        dwconv_kernel<<<1024, 256, 0, stream>>>(xp_c, dw_w + i * 1536, dw_b + i * 512, xcv);
        castw_kernel<<<64, 256, 0, stream>>>(xproj_w + i * 16384, wbuf, 16384);
        xproj_mfma<<<M / 128, 256, 0, stream>>>(xcv, wbuf, xproj_b + i * 32, BC);
        scan_kernel<<<128, 256, 0, stream>>>(BC, xcv, grs, A + i * 8192, D + i * 512,
                                             sn_g + i * 8192, sn_b + i * 8192, yg);
        castw_kernel<<<512, 256, 0, stream>>>(outproj_w + (size_t)i * 131072, wbuf, 131072);
        // outproj + residual: 128x256 tile, N=256 in one block (nbn=1)
        gemm_bt2<3><<<M / 128, 256, 0, stream>>>(yg, wbuf, outproj_b + i * 256, h, h,
                                                 1, 512, 512, 256);
    }
    poolfc_kernel<<<128, 256, 0, stream>>>(h, fc_w, fc_b, out);
}

// Round 13
// 966.120 us; speedup vs baseline: 1.2458x; 1.2458x over previous
//
#include <hip/hip_runtime.h>
#include <hip/hip_bf16.h>
#include <math.h>

#define DEVINL __device__ __forceinline__

typedef __attribute__((ext_vector_type(2))) float  f32x2;
typedef __attribute__((ext_vector_type(4))) float  f32x4;
typedef __attribute__((ext_vector_type(8))) __bf16 bf16x8;
typedef __attribute__((ext_vector_type(8))) unsigned short ushort8;

DEVINL float b2f(unsigned short u) {
    union { unsigned int i; float f; } v; v.i = ((unsigned int)u) << 16; return v.f;
}
DEVINL unsigned short f2b(float f) {
    union { float f; unsigned int i; } v; v.f = f;
    unsigned int u = v.i;
    unsigned int r = (u + 0x7fffu + ((u >> 16) & 1u)) >> 16;
    return (unsigned short)r;
}
DEVINL float gelu_exact(float x) {
    return 0.5f * x * (1.0f + erff(x * 0.70710678118654752440f));
}

// VOP3P packed fp32 (CDNA2+): 2 FLOPs per instruction on register pairs.
DEVINL f32x2 pk_fma(f32x2 a, f32x2 b, f32x2 c) {
    f32x2 d; asm("v_pk_fma_f32 %0, %1, %2, %3" : "=v"(d) : "v"(a), "v"(b), "v"(c)); return d;
}
DEVINL f32x2 pk_add(f32x2 a, f32x2 b) {
    f32x2 d; asm("v_pk_add_f32 %0, %1, %2" : "=v"(d) : "v"(a), "v"(b)); return d;
}
DEVINL f32x2 pk_mul(f32x2 a, f32x2 b) {
    f32x2 d; asm("v_pk_mul_f32 %0, %1, %2" : "=v"(d) : "v"(a), "v"(b)); return d;
}

// Barrier that drains ONLY LDS (lgkmcnt).
DEVINL void bar_lgkm() {
    asm volatile("s_waitcnt lgkmcnt(0)" ::: "memory");
    __builtin_amdgcn_s_barrier();
    __builtin_amdgcn_sched_barrier(0);
}

// LDS XOR swizzle (T2): permute 8-element groups within a 64-elem row by row&7.
DEVINL int swz(int off) { return off ^ (((off >> 6) & 7) << 3); }

// Direct global->LDS async copy, 16B per lane (linear LDS dest, pre-swizzled src).
DEVINL void gload16(const unsigned short* g, unsigned short* l) {
    __builtin_amdgcn_global_load_lds(
        (const __attribute__((address_space(1))) unsigned int*)g,
        (__attribute__((address_space(3))) unsigned int*)l, 16, 0, 0);
}

// DPP-based wave64 sum: result valid in lane 63 of each wave.
template <int CTRL>
DEVINL float dpp_add(float x) {
    int xi = __builtin_bit_cast(int, x);
    int yi = __builtin_amdgcn_update_dpp(0, xi, CTRL, 0xf, 0xf, true);
    return x + __builtin_bit_cast(float, yi);
}
DEVINL float wave_sum63(float x) {
    x = dpp_add<0x111>(x);
    x = dpp_add<0x112>(x);
    x = dpp_add<0x114>(x);
    x = dpp_add<0x118>(x);
    x = dpp_add<0x142>(x);
    x = dpp_add<0x143>(x);
    return x;
}

// ---------------------------------------------------------------------------
// conv1 (Cin=8 -> 256, k=3, pad=1) + ReLU, output bf16.
__global__ __launch_bounds__(256) void conv1_kernel(
    const float* __restrict__ x, const float* __restrict__ w,
    const float* __restrict__ bias, unsigned short* __restrict__ h1)
{
    __shared__ float xs[52 * 8];
    int b = blockIdx.x >> 3, tile = blockIdx.x & 7;
    int p0 = tile * 50;
    int t = threadIdx.x;
    for (int i = t; i < 416; i += 256) {
        int p = i >> 3, c = i & 7;
        int lp = p0 + p - 1;
        xs[i] = (lp >= 0 && lp < 400) ? x[((size_t)b * 400 + lp) * 8 + c] : 0.0f;
    }
    float wr[24];
    const float4* wp = (const float4*)(w + t * 24);
#pragma unroll
    for (int i = 0; i < 6; ++i) {
        float4 v4 = wp[i];
        wr[i * 4] = v4.x; wr[i * 4 + 1] = v4.y; wr[i * 4 + 2] = v4.z; wr[i * 4 + 3] = v4.w;
    }
    float bs = bias[t];
    __syncthreads();
#pragma unroll 2
    for (int p = 0; p < 50; ++p) {
        float acc = bs;
#pragma unroll
        for (int dt = 0; dt < 3; ++dt)
#pragma unroll
            for (int c = 0; c < 8; ++c)
                acc += xs[(p + dt) * 8 + c] * wr[c * 3 + dt];
        h1[((size_t)b * 400 + p0 + p) * 256 + t] = f2b(fmaxf(acc, 0.0f));
    }
}

// conv2 weight reorder (o, ci, t) -> w2r[o, t*256+ci] bf16
__global__ void reorder_w2_kernel(const float* __restrict__ w, unsigned short* __restrict__ out)
{
    int idx = blockIdx.x * 256 + threadIdx.x;
    if (idx >= 256 * 768) return;
    int o = idx / 768, r = idx % 768;
    int tpos = r / 256, ci = r % 256;
    out[idx] = f2b(w[o * 768 + ci * 3 + tpos]);
}

__global__ void castw_kernel(const float* __restrict__ in, unsigned short* __restrict__ out, int n)
{
    int i = blockIdx.x * 256 + threadIdx.x;
    if (i < n) out[i] = f2b(in[i]);
}

// ---------------------------------------------------------------------------
// LayerNorm over dm=256 per row, fp32 in -> bf16 out. 4 rows/block (1/wave).
__global__ __launch_bounds__(256) void ln_kernel(
    const float* __restrict__ h, const float* __restrict__ g,
    const float* __restrict__ bta, unsigned short* __restrict__ out)
{
    int w = threadIdx.x >> 6, l = threadIdx.x & 63;
    int row = blockIdx.x * 4 + w;
    const float* p = h + (size_t)row * 256 + l * 4;
    float4 v = *(const float4*)p;
    float s  = v.x + v.y + v.z + v.w;
    float s2 = v.x * v.x + v.y * v.y + v.z * v.z + v.w * v.w;
#pragma unroll
    for (int m = 1; m < 64; m <<= 1) { s += __shfl_xor(s, m); s2 += __shfl_xor(s2, m); }
    float mu = s * (1.0f / 256.0f);
    float var = s2 * (1.0f / 256.0f) - mu * mu;
    float rs = rsqrtf(var + 1e-5f);
    float4 gg = *(const float4*)(g + l * 4);
    float4 bb = *(const float4*)(bta + l * 4);
    ushort4 o;
    o.x = f2b((v.x - mu) * rs * gg.x + bb.x);
    o.y = f2b((v.y - mu) * rs * gg.y + bb.y);
    o.z = f2b((v.z - mu) * rs * gg.z + bb.z);
    o.w = f2b((v.w - mu) * rs * gg.w + bb.w);
    *(ushort4*)(out + (size_t)row * 256 + l * 4) = o;
}

// ---------------------------------------------------------------------------
// bf16 GEMM, 128x128 tile: C(MxN) = A(MxK, lda) * Bt(NxK)^T.
// Staging: global_load_lds (16B/lane, linear LDS dest) with pre-swizzled source.
// EPI 0: +bias bf16.  1: +bias GELU bf16.  3: +bias+res fp32.
// EPI 4 (fused inproj): col<512 -> plain bf16; col>=512 -> GELU bf16 to res.
template <int EPI>
__global__ __launch_bounds__(256) void gemm_bt(
    const unsigned short* __restrict__ A, const unsigned short* __restrict__ Bt,
    const float* __restrict__ bias, const float* __restrict__ res,
    void* __restrict__ Cout, int N, int K, int lda, int ldc)
{
    __shared__ unsigned short As[128 * 64];
    __shared__ unsigned short Bs[128 * 64];
    const int nbn = N >> 7;
    int bm = blockIdx.x / nbn, bn = blockIdx.x % nbn;
    int t = threadIdx.x, l = t & 63, w = t >> 6;
    int wm = w & 1, wn = w >> 1;
    int srow = t >> 3;
    int scol = 8 * ((t & 7) ^ ((t >> 3) & 7));
    f32x4 acc[4][4] = {};
    const int ktn = K >> 6;
    for (int kt = 0; kt < ktn; ++kt) {
#pragma unroll
        for (int i = 0; i < 4; ++i) {
            int row = i * 32 + srow;
            gload16(A + (size_t)(bm * 128 + row) * lda + kt * 64 + scol,
                    As + (i * 256 + w * 64) * 8);
            gload16(Bt + (size_t)(bn * 128 + row) * K + kt * 64 + scol,
                    Bs + (i * 256 + w * 64) * 8);
        }
        __syncthreads();
#pragma unroll
        for (int kk = 0; kk < 2; ++kk) {
            bf16x8 af[4], bfr[4];
#pragma unroll
            for (int i = 0; i < 4; ++i) {
                af[i]  = *(const bf16x8*)(As + swz((wm * 64 + i * 16 + (l & 15)) * 64 + kk * 32 + (l >> 4) * 8));
                bfr[i] = *(const bf16x8*)(Bs + swz((wn * 64 + i * 16 + (l & 15)) * 64 + kk * 32 + (l >> 4) * 8));
            }
#pragma unroll
            for (int i = 0; i < 4; ++i)
#pragma unroll
                for (int j = 0; j < 4; ++j)
                    acc[i][j] = __builtin_amdgcn_mfma_f32_16x16x32_bf16(af[i], bfr[j], acc[i][j], 0, 0, 0);
        }
        __syncthreads();
    }
    int r0 = bm * 128 + wm * 64 + (l >> 4) * 4;
    int c0 = bn * 128 + wn * 64 + (l & 15);
#pragma unroll
    for (int i = 0; i < 4; ++i) {
#pragma unroll
        for (int j = 0; j < 4; ++j) {
            int col = c0 + j * 16;
            float bb = bias[col];
#pragma unroll
            for (int q = 0; q < 4; ++q) {
                int row = r0 + i * 16 + q;
                float v = acc[i][j][q] + bb;
                if (EPI == 0) {
                    ((unsigned short*)Cout)[(size_t)row * ldc + col] = f2b(v);
                } else if (EPI == 1) {
                    ((unsigned short*)Cout)[(size_t)row * ldc + col] = f2b(gelu_exact(v));
                } else if (EPI == 3) {
                    size_t idx = (size_t)row * ldc + col;
                    ((float*)Cout)[idx] = v + res[idx];
                } else {    // EPI 4: fused inproj split epilogue
                    if (col < 512)
                        ((unsigned short*)Cout)[(size_t)row * 512 + col] = f2b(v);
                    else
                        ((unsigned short*)res)[(size_t)row * 512 + (col - 512)] = f2b(gelu_exact(v));
                }
            }
        }
    }
}

// ---------------------------------------------------------------------------
// conv2 as GEMM with FUSED im2col staging (reg-staged: needs boundary zeros).
__global__ __launch_bounds__(256) void gemm_conv2(
    const unsigned short* __restrict__ h1, const unsigned short* __restrict__ Bt,
    const float* __restrict__ bias, float* __restrict__ Cout)
{
    __shared__ unsigned short As[128 * 64];
    __shared__ unsigned short Bs[128 * 64];
    int bm = blockIdx.x >> 1, bn = blockIdx.x & 1;
    int t = threadIdx.x, l = t & 63, w = t >> 6;
    int wm = w & 1, wn = w >> 1;
    f32x4 acc[4][4] = {};
    for (int kt = 0; kt < 12; ++kt) {
        int tpos = kt >> 2;
        int cbase = (kt & 3) * 64;
#pragma unroll
        for (int i = 0; i < 4; ++i) {
            int off = (i * 256 + t) * 8;
            int row = off >> 6, col = off & 63;
            int m = bm * 128 + row;
            int b = m / 400, ll = m % 400;
            int lp = ll + tpos - 1;
            ushort8 va = (ushort8)0;
            if (lp >= 0 && lp < 400)
                va = *(const ushort8*)(h1 + ((size_t)(b * 400 + lp) * 256 + cbase + col));
            *(ushort8*)(As + swz(off)) = va;
            ushort8 vb = *(const ushort8*)(Bt + (size_t)(bn * 128 + row) * 768 + kt * 64 + col);
            *(ushort8*)(Bs + swz(off)) = vb;
        }
        __syncthreads();
#pragma unroll
        for (int kk = 0; kk < 2; ++kk) {
            bf16x8 af[4], bfr[4];
#pragma unroll
            for (int i = 0; i < 4; ++i) {
                af[i]  = *(const bf16x8*)(As + swz((wm * 64 + i * 16 + (l & 15)) * 64 + kk * 32 + (l >> 4) * 8));
                bfr[i] = *(const bf16x8*)(Bs + swz((wn * 64 + i * 16 + (l & 15)) * 64 + kk * 32 + (l >> 4) * 8));
            }
#pragma unroll
            for (int i = 0; i < 4; ++i)
#pragma unroll
                for (int j = 0; j < 4; ++j)
                    acc[i][j] = __builtin_amdgcn_mfma_f32_16x16x32_bf16(af[i], bfr[j], acc[i][j], 0, 0, 0);
        }
        __syncthreads();
    }
    int r0 = bm * 128 + wm * 64 + (l >> 4) * 4;
    int c0 = bn * 128 + wn * 64 + (l & 15);
#pragma unroll
    for (int i = 0; i < 4; ++i)
#pragma unroll
        for (int j = 0; j < 4; ++j) {
            int col = c0 + j * 16;
            float bb = bias[col];
#pragma unroll
            for (int q = 0; q < 4; ++q) {
                int row = r0 + i * 16 + q;
                Cout[(size_t)row * 256 + col] = fmaxf(acc[i][j][q] + bb, 0.0f);
            }
        }
}

// ---------------------------------------------------------------------------
// depthwise conv (k=3, pad=1) + GELU; bf16 in/out; register-sliding window.
__global__ __launch_bounds__(256) void dwconv_kernel(
    const unsigned short* __restrict__ xp, const float* __restrict__ w,
    const float* __restrict__ bias, unsigned short* __restrict__ out)
{
    int b = blockIdx.x >> 3, tile = blockIdx.x & 7;
    int p0 = tile * 50;
    int t = threadIdx.x;
    int c = t * 2;
    float w00 = w[c * 3], w01 = w[c * 3 + 1], w02 = w[c * 3 + 2];
    float w10 = w[c * 3 + 3], w11 = w[c * 3 + 4], w12 = w[c * 3 + 5];
    float b0 = bias[c], b1 = bias[c + 1];
    const size_t rowb = (size_t)b * 400;
    int l = p0;
    unsigned int r0 = (l - 1 >= 0) ? *(const unsigned int*)(xp + (rowb + l - 1) * 512 + c) : 0u;
    unsigned int r1 = *(const unsigned int*)(xp + (rowb + l) * 512 + c);
    for (int q = 0; q < 50; ++q, ++l) {
        unsigned int r2 = (l + 1 < 400) ? *(const unsigned int*)(xp + (rowb + l + 1) * 512 + c) : 0u;
        float a0 = b0 + b2f((unsigned short)(r0 & 0xffff)) * w00
                      + b2f((unsigned short)(r1 & 0xffff)) * w01
                      + b2f((unsigned short)(r2 & 0xffff)) * w02;
        float a1 = b1 + b2f((unsigned short)(r0 >> 16)) * w10
                      + b2f((unsigned short)(r1 >> 16)) * w11
                      + b2f((unsigned short)(r2 >> 16)) * w12;
        unsigned int o = (unsigned int)f2b(gelu_exact(a0)) | ((unsigned int)f2b(gelu_exact(a1)) << 16);
        *(unsigned int*)(out + (rowb + l) * 512 + c) = o;
        r0 = r1; r1 = r2;
    }
}

// ---------------------------------------------------------------------------
// xproj as MFMA GEMM: BC(M x 32) = tanh(xcv(M x 512) @ W^T(32x512) + b).
__global__ __launch_bounds__(256) void xproj_mfma(
    const unsigned short* __restrict__ xc, const unsigned short* __restrict__ w,
    const float* __restrict__ bias, float* __restrict__ BC)
{
    __shared__ unsigned short As[128 * 64];
    __shared__ unsigned short Bs[32 * 64];
    int bm = blockIdx.x;
    int t = threadIdx.x, l = t & 63, wv = t >> 6;
    f32x4 acc[2][2] = {};
    for (int kt = 0; kt < 8; ++kt) {
#pragma unroll
        for (int i = 0; i < 4; ++i) {
            int off = (i * 256 + t) * 8;
            int row = off >> 6, col = off & 63;
            ushort8 va = *(const ushort8*)(xc + (size_t)(bm * 128 + row) * 512 + kt * 64 + col);
            *(ushort8*)(As + swz(off)) = va;
        }
        {
            int off = t * 8;
            int row = off >> 6, col = off & 63;
            ushort8 vb = *(const ushort8*)(w + (size_t)row * 512 + kt * 64 + col);
            *(ushort8*)(Bs + swz(off)) = vb;
        }
        __syncthreads();
#pragma unroll
        for (int kk = 0; kk < 2; ++kk) {
            bf16x8 af[2], bfr[2];
#pragma unroll
            for (int i = 0; i < 2; ++i) {
                af[i]  = *(const bf16x8*)(As + swz((wv * 32 + i * 16 + (l & 15)) * 64 + kk * 32 + (l >> 4) * 8));
                bfr[i] = *(const bf16x8*)(Bs + swz((i * 16 + (l & 15)) * 64 + kk * 32 + (l >> 4) * 8));
            }
#pragma unroll
            for (int i = 0; i < 2; ++i)
#pragma unroll
                for (int j = 0; j < 2; ++j)
                    acc[i][j] = __builtin_amdgcn_mfma_f32_16x16x32_bf16(af[i], bfr[j], acc[i][j], 0, 0, 0);
        }
        __syncthreads();
    }
    int r0 = bm * 128 + wv * 32 + (l >> 4) * 4;
    int c0 = l & 15;
#pragma unroll
    for (int i = 0; i < 2; ++i)
#pragma unroll
        for (int j = 0; j < 2; ++j) {
            int col = c0 + j * 16;
            float bb = bias[col];
#pragma unroll
            for (int q = 0; q < 4; ++q) {
                int row = r0 + i * 16 + q;
                BC[(size_t)row * 32 + col] = tanhf(acc[i][j][q] + bb);
            }
        }
}

// ---------------------------------------------------------------------------
// Sequential SSM scan. 256 threads (4 waves), 2 channels/thread (32 states).
// 50 chunks x 8 unrolled phases, register-resident operands, counted-lgkmcnt
// pre-barrier prefetch. (round-11 structure — best measured: ~265 us)
__global__ __launch_bounds__(256) void scan_kernel(
    const float* __restrict__ BC, const unsigned short* __restrict__ xconv,
    const unsigned short* __restrict__ gres, const float* __restrict__ Aw,
    const float* __restrict__ Dw, const float* __restrict__ sng,
    const float* __restrict__ snb, unsigned short* __restrict__ yg)
{
    __shared__ __align__(16) unsigned short lds_x[2][4096];
    __shared__ __align__(16) unsigned short lds_g[2][4096];
    __shared__ __align__(16) float lds_bc[2][256];
    __shared__ __align__(16) float lds_s1[2][4];
    __shared__ __align__(16) float lds_s2[2][4];
    int b = blockIdx.x, t = threadIdx.x;
    int d0 = t * 2;
    f32x2 st2[16], tA2[16], g2[16], bb2[16];
#pragma unroll
    for (int ch = 0; ch < 2; ++ch)
#pragma unroll
        for (int j = 0; j < 8; ++j) {
            int idx = ch * 8 + j;
            st2[idx] = (f32x2)(0.0f);
            f32x2 av = *(const f32x2*)(Aw + (d0 + ch) * 16 + j * 2);
            tA2[idx] = (f32x2){tanhf(av.x), tanhf(av.y)};
            g2[idx]  = *(const f32x2*)(sng + (d0 + ch) * 16 + j * 2);
            bb2[idx] = *(const f32x2*)(snb + (d0 + ch) * 16 + j * 2);
        }
    f32x2 Dd = *(const f32x2*)(Dw + d0);
    const size_t base = (size_t)b * 400;
    {
        size_t o = base * 512 + t * 16;
        *(ushort8*)(&lds_x[0][t * 16])     = *(const ushort8*)(xconv + o);
        *(ushort8*)(&lds_x[0][t * 16 + 8]) = *(const ushort8*)(xconv + o + 8);
        *(ushort8*)(&lds_g[0][t * 16])     = *(const ushort8*)(gres + o);
        *(ushort8*)(&lds_g[0][t * 16 + 8]) = *(const ushort8*)(gres + o + 8);
        if (t < 64) *(float4*)(&lds_bc[0][t * 4]) = *(const float4*)(BC + base * 32 + t * 4);
    }
    bar_lgkm();
    float4 bcv[8];
#pragma unroll
    for (int q = 0; q < 8; ++q) bcv[q] = *(const float4*)&lds_bc[0][q * 4];
    unsigned int cxr = *(const unsigned int*)&lds_x[0][d0];
    unsigned int cgr = *(const unsigned int*)&lds_g[0][d0];
    ushort8 xr0, xr1, gr0, gr1; float4 bc_r;
    for (int c = 0; c < 50; ++c) {
        int cur = c & 1;
        const size_t lbase = base + c * 8;
#pragma unroll
        for (int pp = 0; pp < 8; ++pp) {
            if (pp == 0 && c + 1 < 50) {
                size_t o = (lbase + 8) * 512 + t * 16;
                xr0 = *(const ushort8*)(xconv + o);
                xr1 = *(const ushort8*)(xconv + o + 8);
                gr0 = *(const ushort8*)(gres + o);
                gr1 = *(const ushort8*)(gres + o + 8);
                if (t < 64) bc_r = *(const float4*)(BC + (lbase + 8) * 32 + t * 4);
            }
            const f32x2* Bp = (const f32x2*)&bcv[0];
            const f32x2* Cp = (const f32x2*)&bcv[4];
            float x0 = b2f((unsigned short)(cxr & 0xffff)), x1 = b2f((unsigned short)(cxr >> 16));
            float ga0 = b2f((unsigned short)(cgr & 0xffff)), ga1 = b2f((unsigned short)(cgr >> 16));
            f32x2 o0A = (f32x2){x0 * Dd.x, 0.0f}, o0B = (f32x2)(0.0f);
            f32x2 o1A = (f32x2){x1 * Dd.y, 0.0f}, o1B = (f32x2)(0.0f);
#pragma unroll
            for (int j = 0; j < 8; j += 2) {
                st2[j]     = pk_add(st2[j],     Bp[j]);     o0A = pk_fma(st2[j],     Cp[j],     o0A);
                st2[j + 1] = pk_add(st2[j + 1], Bp[j + 1]); o0B = pk_fma(st2[j + 1], Cp[j + 1], o0B);
                st2[8 + j]     = pk_add(st2[8 + j],     Bp[j]);     o1A = pk_fma(st2[8 + j],     Cp[j],     o1A);
                st2[8 + j + 1] = pk_add(st2[8 + j + 1], Bp[j + 1]); o1B = pk_fma(st2[8 + j + 1], Cp[j + 1], o1B);
            }
            f32x2 o0 = pk_add(o0A, o0B), o1 = pk_add(o1A, o1B);
            unsigned int oy = (unsigned int)f2b((o0.x + o0.y) * ga0)
                            | ((unsigned int)f2b((o1.x + o1.y) * ga1) << 16);
            *(unsigned int*)(yg + (lbase + pp) * 512 + d0) = oy;
            f32x2 sA = (f32x2)(0.0f), sB = (f32x2)(0.0f), sC = (f32x2)(0.0f), sD = (f32x2)(0.0f);
            f32x2 qA = (f32x2)(0.0f), qB = (f32x2)(0.0f), qC = (f32x2)(0.0f), qD = (f32x2)(0.0f);
#pragma unroll
            for (int j = 0; j < 16; j += 4) {
                st2[j]     = pk_mul(st2[j],     tA2[j]);     sA = pk_add(sA, st2[j]);     qA = pk_fma(st2[j],     st2[j],     qA);
                st2[j + 1] = pk_mul(st2[j + 1], tA2[j + 1]); sB = pk_add(sB, st2[j + 1]); qB = pk_fma(st2[j + 1], st2[j + 1], qB);
                st2[j + 2] = pk_mul(st2[j + 2], tA2[j + 2]); sC = pk_add(sC, st2[j + 2]); qC = pk_fma(st2[j + 2], st2[j + 2], qC);
                st2[j + 3] = pk_mul(st2[j + 3], tA2[j + 3]); sD = pk_add(sD, st2[j + 3]); qD = pk_fma(st2[j + 3], st2[j + 3], qD);
            }
            f32x2 sS = pk_add(pk_add(sA, sB), pk_add(sC, sD));
            f32x2 qS = pk_add(pk_add(qA, qB), pk_add(qC, qD));
            float s1 = wave_sum63(sS.x + sS.y);
            float s2 = wave_sum63(qS.x + qS.y);
            if (pp == 6 && c + 1 < 50) {
                if (t < 64) *(float4*)(&lds_bc[cur ^ 1][t * 4]) = bc_r;
            }
            if (pp == 7 && c + 1 < 50) {
                *(ushort8*)(&lds_x[cur ^ 1][t * 16])     = xr0;
                *(ushort8*)(&lds_x[cur ^ 1][t * 16 + 8]) = xr1;
                *(ushort8*)(&lds_g[cur ^ 1][t * 16])     = gr0;
                *(ushort8*)(&lds_g[cur ^ 1][t * 16 + 8]) = gr1;
            }
            if ((t & 63) == 63) { lds_s1[pp & 1][t >> 6] = s1; lds_s2[pp & 1][t >> 6] = s2; }
            __builtin_amdgcn_sched_barrier(0);
            float4 nbc[8]; unsigned int nxr = 0, ngr = 0;
            if (pp < 7) {
#pragma unroll
                for (int q = 0; q < 8; ++q)
                    nbc[q] = *(const float4*)&lds_bc[cur][(pp + 1) * 32 + q * 4];
                nxr = *(const unsigned int*)&lds_x[cur][(pp + 1) * 512 + d0];
                ngr = *(const unsigned int*)&lds_g[cur][(pp + 1) * 512 + d0];
                __builtin_amdgcn_sched_barrier(0);
                asm volatile("s_waitcnt lgkmcnt(10)" ::: "memory");
            } else if (c + 1 < 50) {
#pragma unroll
                for (int q = 0; q < 8; ++q)
                    nbc[q] = *(const float4*)&lds_bc[cur ^ 1][q * 4];
                __builtin_amdgcn_sched_barrier(0);
                asm volatile("s_waitcnt lgkmcnt(8)" ::: "memory");
            } else {
                asm volatile("s_waitcnt lgkmcnt(0)" ::: "memory");
            }
            __builtin_amdgcn_s_barrier();
            __builtin_amdgcn_sched_barrier(0);
            float4 p0v = *(const float4*)&lds_s1[pp & 1][0];
            float4 r0v = *(const float4*)&lds_s2[pp & 1][0];
            float S1 = (p0v.x + p0v.y) + (p0v.z + p0v.w);
            float S2 = (r0v.x + r0v.y) + (r0v.z + r0v.w);
            float mu = S1 * (1.0f / 8192.0f);
            float var = S2 * (1.0f / 8192.0f) - mu * mu;
            float rs = rsqrtf(var + 1e-5f);
            f32x2 rs2 = (f32x2){rs, rs};
            f32x2 nm2 = (f32x2){-mu * rs, -mu * rs};
#pragma unroll
            for (int j = 0; j < 16; ++j) {
                f32x2 zn = pk_fma(st2[j], rs2, nm2);
                st2[j] = pk_fma(zn, g2[j], bb2[j]);
            }
            if (pp < 7) {
#pragma unroll
                for (int q = 0; q < 8; ++q) bcv[q] = nbc[q];
                cxr = nxr; cgr = ngr;
            } else if (c + 1 < 50) {
#pragma unroll
                for (int q = 0; q < 8; ++q) bcv[q] = nbc[q];
                cxr = *(const unsigned int*)&lds_x[cur ^ 1][d0];
                cgr = *(const unsigned int*)&lds_g[cur ^ 1][d0];
            }
        }
    }
}

// ---------------------------------------------------------------------------
// mean over L then FC (37 classes). 1 block per batch.
__global__ __launch_bounds__(256) void poolfc_kernel(
    const float* __restrict__ h, const float* __restrict__ fcw,
    const float* __restrict__ fcb, float* __restrict__ out)
{
    __shared__ float ps[256];
    int b = blockIdx.x, t = threadIdx.x;
    float s = 0.0f;
    for (int l = 0; l < 400; ++l) s += h[((size_t)b * 400 + l) * 256 + t];
    ps[t] = s * (1.0f / 400.0f);
    __syncthreads();
    if (t < 37) {
        float acc = fcb[t];
        for (int o = 0; o < 256; ++o) acc += ps[o] * fcw[t * 256 + o];
        out[b * 37 + t] = acc;
    }
}

// ---------------------------------------------------------------------------
extern "C" void kernel_launch(void* const* d_in, const int* in_sizes, int n_in,
                              void* d_out, int out_size, void* d_ws, size_t ws_size,
                              hipStream_t stream)
{
    const float* x         = (const float*)d_in[0];
    const float* conv1_w   = (const float*)d_in[1];
    const float* conv1_b   = (const float*)d_in[2];
    const float* conv2_w   = (const float*)d_in[3];
    const float* conv2_b   = (const float*)d_in[4];
    const float* ln_g      = (const float*)d_in[5];
    const float* ln_b      = (const float*)d_in[6];
    const float* inproj_w  = (const float*)d_in[7];
    const float* inproj_b  = (const float*)d_in[8];
    const float* dw_w      = (const float*)d_in[9];
    const float* dw_b      = (const float*)d_in[10];
    const float* xproj_w   = (const float*)d_in[11];
    const float* xproj_b   = (const float*)d_in[12];
    const float* A         = (const float*)d_in[13];
    const float* D         = (const float*)d_in[14];
    const float* sn_g      = (const float*)d_in[15];
    const float* sn_b      = (const float*)d_in[16];
    const float* outproj_w = (const float*)d_in[17];
    const float* outproj_b = (const float*)d_in[18];
    const float* fc_w      = (const float*)d_in[19];
    const float* fc_b      = (const float*)d_in[20];
    float* out = (float*)d_out;

    const int M = 51200; // B*L

    // Workspace: big buffers (243,007,488) + hoisted weight area (2,031,616)
    if (ws_size < 244514816u) return;
    char* ws = (char*)d_ws;
    float*          h    = (float*)(ws);
    unsigned short* hn   = (unsigned short*)(ws + 52428800);
    unsigned short* h1   = (unsigned short*)(ws + 52428800);
    unsigned short* xp_c = (unsigned short*)(ws + 78643200);
    unsigned short* yg   = (unsigned short*)(ws + 78643200);
    unsigned short* grs  = (unsigned short*)(ws + 131072000);
    unsigned short* xcv  = (unsigned short*)(ws + 183500800);
    float*          BC   = (float*)(ws + 235929600);
    // hoisted weight area
    unsigned short* wb   = (unsigned short*)(ws + 242483200);
    unsigned short* w2r   = wb;                       // 196,608 elems
    unsigned short* winp0 = wb + 196608;              // 262,144
    unsigned short* winp1 = wb + 458752;              // 262,144
    unsigned short* wxp0  = wb + 720896;              // 16,384
    unsigned short* wxp1  = wb + 737280;              // 16,384
    unsigned short* wout0 = wb + 753664;              // 131,072
    unsigned short* wout1 = wb + 884736;              // 131,072  (end: 1,015,808 elems = 2,031,616 B)
    unsigned short* winp[2] = {winp0, winp1};
    unsigned short* wxp[2]  = {wxp0, wxp1};
    unsigned short* wout[2] = {wout0, wout1};

    // --- hoisted weight prep (once, before the big pipeline) ---
    reorder_w2_kernel<<<768, 256, 0, stream>>>(conv2_w, w2r);
    for (int i = 0; i < 2; ++i) {
        castw_kernel<<<1024, 256, 0, stream>>>(inproj_w + (size_t)i * 262144, winp[i], 262144);
        castw_kernel<<<64, 256, 0, stream>>>(xproj_w + i * 16384, wxp[i], 16384);
        castw_kernel<<<512, 256, 0, stream>>>(outproj_w + (size_t)i * 131072, wout[i], 131072);
    }

    // conv1 + relu -> h1 (bf16); conv2 GEMM (fused im2col) + relu -> h (fp32)
    conv1_kernel<<<128 * 8, 256, 0, stream>>>(x, conv1_w, conv1_b, h1);
    gemm_conv2<<<(M / 128) * 2, 256, 0, stream>>>(h1, w2r, conv2_b, h);

    for (int i = 0; i < 2; ++i) {
        ln_kernel<<<M / 4, 256, 0, stream>>>(h, ln_g + i * 256, ln_b + i * 256, hn);
        // fused inproj: N=1024, split epilogue (xp_c plain / grs GELU)
        gemm_bt<4><<<(M / 128) * 8, 256, 0, stream>>>(hn, winp[i], inproj_b + i * 1024,
                                                      (const float*)grs, xp_c, 1024, 256, 256, 512);
        dwconv_kernel<<<1024, 256, 0, stream>>>(xp_c, dw_w + i * 1536, dw_b + i * 512, xcv);
        xproj_mfma<<<M / 128, 256, 0, stream>>>(xcv, wxp[i], xproj_b + i * 32, BC);
        scan_kernel<<<128, 256, 0, stream>>>(BC, xcv, grs, A + i * 8192, D + i * 512,
                                             sn_g + i * 8192, sn_b + i * 8192, yg);
        // outproj + residual -> h (fp32, in place)
        gemm_bt<3><<<(M / 128) * 2, 256, 0, stream>>>(yg, wout[i], outproj_b + i * 256, h, h,
                                                      256, 512, 512, 256);
    }
    poolfc_kernel<<<128, 256, 0, stream>>>(h, fc_w, fc_b, out);
}

// Round 14
// 937.935 us; speedup vs baseline: 1.2832x; 1.0301x over previous
//
#include <hip/hip_runtime.h>
#include <hip/hip_bf16.h>
#include <math.h>

#define DEVINL __device__ __forceinline__

typedef __attribute__((ext_vector_type(2))) float  f32x2;
typedef __attribute__((ext_vector_type(4))) float  f32x4;
typedef __attribute__((ext_vector_type(8))) __bf16 bf16x8;
typedef __attribute__((ext_vector_type(8))) unsigned short ushort8;

DEVINL float b2f(unsigned short u) {
    union { unsigned int i; float f; } v; v.i = ((unsigned int)u) << 16; return v.f;
}
DEVINL unsigned short f2b(float f) {
    union { float f; unsigned int i; } v; v.f = f;
    unsigned int u = v.i;
    unsigned int r = (u + 0x7fffu + ((u >> 16) & 1u)) >> 16;
    return (unsigned short)r;
}
DEVINL float gelu_exact(float x) {
    return 0.5f * x * (1.0f + erff(x * 0.70710678118654752440f));
}

// VOP3P packed fp32 (CDNA2+): 2 FLOPs per instruction on register pairs.
DEVINL f32x2 pk_fma(f32x2 a, f32x2 b, f32x2 c) {
    f32x2 d; asm("v_pk_fma_f32 %0, %1, %2, %3" : "=v"(d) : "v"(a), "v"(b), "v"(c)); return d;
}
DEVINL f32x2 pk_add(f32x2 a, f32x2 b) {
    f32x2 d; asm("v_pk_add_f32 %0, %1, %2" : "=v"(d) : "v"(a), "v"(b)); return d;
}
DEVINL f32x2 pk_mul(f32x2 a, f32x2 b) {
    f32x2 d; asm("v_pk_mul_f32 %0, %1, %2" : "=v"(d) : "v"(a), "v"(b)); return d;
}

// Barrier that drains ONLY LDS (lgkmcnt).
DEVINL void bar_lgkm() {
    asm volatile("s_waitcnt lgkmcnt(0)" ::: "memory");
    __builtin_amdgcn_s_barrier();
    __builtin_amdgcn_sched_barrier(0);
}

// LDS XOR swizzle (T2): permute 8-element groups within a 64-elem row by row&7.
DEVINL int swz(int off) { return off ^ (((off >> 6) & 7) << 3); }

// Direct global->LDS async copy, 16B per lane (linear LDS dest, pre-swizzled src).
DEVINL void gload16(const unsigned short* g, unsigned short* l) {
    __builtin_amdgcn_global_load_lds(
        (const __attribute__((address_space(1))) unsigned int*)g,
        (__attribute__((address_space(3))) unsigned int*)l, 16, 0, 0);
}

// DPP-based wave64 sum: result valid in lane 63 of each wave.
template <int CTRL>
DEVINL float dpp_add(float x) {
    int xi = __builtin_bit_cast(int, x);
    int yi = __builtin_amdgcn_update_dpp(0, xi, CTRL, 0xf, 0xf, true);
    return x + __builtin_bit_cast(float, yi);
}
DEVINL float wave_sum63(float x) {
    x = dpp_add<0x111>(x);
    x = dpp_add<0x112>(x);
    x = dpp_add<0x114>(x);
    x = dpp_add<0x118>(x);
    x = dpp_add<0x142>(x);
    x = dpp_add<0x143>(x);
    return x;
}

// ---------------------------------------------------------------------------
// conv1 (Cin=8 -> 256, k=3, pad=1) + ReLU, output bf16.
__global__ __launch_bounds__(256) void conv1_kernel(
    const float* __restrict__ x, const float* __restrict__ w,
    const float* __restrict__ bias, unsigned short* __restrict__ h1)
{
    __shared__ float xs[52 * 8];
    int b = blockIdx.x >> 3, tile = blockIdx.x & 7;
    int p0 = tile * 50;
    int t = threadIdx.x;
    for (int i = t; i < 416; i += 256) {
        int p = i >> 3, c = i & 7;
        int lp = p0 + p - 1;
        xs[i] = (lp >= 0 && lp < 400) ? x[((size_t)b * 400 + lp) * 8 + c] : 0.0f;
    }
    float wr[24];
    const float4* wp = (const float4*)(w + t * 24);
#pragma unroll
    for (int i = 0; i < 6; ++i) {
        float4 v4 = wp[i];
        wr[i * 4] = v4.x; wr[i * 4 + 1] = v4.y; wr[i * 4 + 2] = v4.z; wr[i * 4 + 3] = v4.w;
    }
    float bs = bias[t];
    __syncthreads();
#pragma unroll 2
    for (int p = 0; p < 50; ++p) {
        float acc = bs;
#pragma unroll
        for (int dt = 0; dt < 3; ++dt)
#pragma unroll
            for (int c = 0; c < 8; ++c)
                acc += xs[(p + dt) * 8 + c] * wr[c * 3 + dt];
        h1[((size_t)b * 400 + p0 + p) * 256 + t] = f2b(fmaxf(acc, 0.0f));
    }
}

// conv2 weight reorder (o, ci, t) -> w2r[o, t*256+ci] bf16
__global__ void reorder_w2_kernel(const float* __restrict__ w, unsigned short* __restrict__ out)
{
    int idx = blockIdx.x * 256 + threadIdx.x;
    if (idx >= 256 * 768) return;
    int o = idx / 768, r = idx % 768;
    int tpos = r / 256, ci = r % 256;
    out[idx] = f2b(w[o * 768 + ci * 3 + tpos]);
}

__global__ void castw_kernel(const float* __restrict__ in, unsigned short* __restrict__ out, int n)
{
    int i = blockIdx.x * 256 + threadIdx.x;
    if (i < n) out[i] = f2b(in[i]);
}

// ---------------------------------------------------------------------------
// LayerNorm over dm=256 per row, fp32 in -> bf16 out. 4 rows/block (1/wave).
__global__ __launch_bounds__(256) void ln_kernel(
    const float* __restrict__ h, const float* __restrict__ g,
    const float* __restrict__ bta, unsigned short* __restrict__ out)
{
    int w = threadIdx.x >> 6, l = threadIdx.x & 63;
    int row = blockIdx.x * 4 + w;
    const float* p = h + (size_t)row * 256 + l * 4;
    float4 v = *(const float4*)p;
    float s  = v.x + v.y + v.z + v.w;
    float s2 = v.x * v.x + v.y * v.y + v.z * v.z + v.w * v.w;
#pragma unroll
    for (int m = 1; m < 64; m <<= 1) { s += __shfl_xor(s, m); s2 += __shfl_xor(s2, m); }
    float mu = s * (1.0f / 256.0f);
    float var = s2 * (1.0f / 256.0f) - mu * mu;
    float rs = rsqrtf(var + 1e-5f);
    float4 gg = *(const float4*)(g + l * 4);
    float4 bb = *(const float4*)(bta + l * 4);
    ushort4 o;
    o.x = f2b((v.x - mu) * rs * gg.x + bb.x);
    o.y = f2b((v.y - mu) * rs * gg.y + bb.y);
    o.z = f2b((v.z - mu) * rs * gg.z + bb.z);
    o.w = f2b((v.w - mu) * rs * gg.w + bb.w);
    *(ushort4*)(out + (size_t)row * 256 + l * 4) = o;
}

// ---------------------------------------------------------------------------
// bf16 GEMM, 128x128 tile: C(MxN) = A(MxK, lda) * Bt(NxK)^T.
// Staging: global_load_lds (16B/lane, linear LDS dest) with pre-swizzled source.
// EPI 0: +bias bf16.  1: +bias GELU bf16.  3: +bias+res fp32.
// EPI 4 (fused inproj): col<512 -> plain bf16; col>=512 -> GELU bf16 to res.
template <int EPI>
__global__ __launch_bounds__(256) void gemm_bt(
    const unsigned short* __restrict__ A, const unsigned short* __restrict__ Bt,
    const float* __restrict__ bias, const float* __restrict__ res,
    void* __restrict__ Cout, int N, int K, int lda, int ldc)
{
    __shared__ unsigned short As[128 * 64];
    __shared__ unsigned short Bs[128 * 64];
    const int nbn = N >> 7;
    int bm = blockIdx.x / nbn, bn = blockIdx.x % nbn;
    int t = threadIdx.x, l = t & 63, w = t >> 6;
    int wm = w & 1, wn = w >> 1;
    int srow = t >> 3;
    int scol = 8 * ((t & 7) ^ ((t >> 3) & 7));
    f32x4 acc[4][4] = {};
    const int ktn = K >> 6;
    for (int kt = 0; kt < ktn; ++kt) {
#pragma unroll
        for (int i = 0; i < 4; ++i) {
            int row = i * 32 + srow;
            gload16(A + (size_t)(bm * 128 + row) * lda + kt * 64 + scol,
                    As + (i * 256 + w * 64) * 8);
            gload16(Bt + (size_t)(bn * 128 + row) * K + kt * 64 + scol,
                    Bs + (i * 256 + w * 64) * 8);
        }
        __syncthreads();
#pragma unroll
        for (int kk = 0; kk < 2; ++kk) {
            bf16x8 af[4], bfr[4];
#pragma unroll
            for (int i = 0; i < 4; ++i) {
                af[i]  = *(const bf16x8*)(As + swz((wm * 64 + i * 16 + (l & 15)) * 64 + kk * 32 + (l >> 4) * 8));
                bfr[i] = *(const bf16x8*)(Bs + swz((wn * 64 + i * 16 + (l & 15)) * 64 + kk * 32 + (l >> 4) * 8));
            }
#pragma unroll
            for (int i = 0; i < 4; ++i)
#pragma unroll
                for (int j = 0; j < 4; ++j)
                    acc[i][j] = __builtin_amdgcn_mfma_f32_16x16x32_bf16(af[i], bfr[j], acc[i][j], 0, 0, 0);
        }
        __syncthreads();
    }
    int r0 = bm * 128 + wm * 64 + (l >> 4) * 4;
    int c0 = bn * 128 + wn * 64 + (l & 15);
#pragma unroll
    for (int i = 0; i < 4; ++i) {
#pragma unroll
        for (int j = 0; j < 4; ++j) {
            int col = c0 + j * 16;
            float bb = bias[col];
#pragma unroll
            for (int q = 0; q < 4; ++q) {
                int row = r0 + i * 16 + q;
                float v = acc[i][j][q] + bb;
                if (EPI == 0) {
                    ((unsigned short*)Cout)[(size_t)row * ldc + col] = f2b(v);
                } else if (EPI == 1) {
                    ((unsigned short*)Cout)[(size_t)row * ldc + col] = f2b(gelu_exact(v));
                } else if (EPI == 3) {
                    size_t idx = (size_t)row * ldc + col;
                    ((float*)Cout)[idx] = v + res[idx];
                } else {    // EPI 4: fused inproj split epilogue
                    if (col < 512)
                        ((unsigned short*)Cout)[(size_t)row * 512 + col] = f2b(v);
                    else
                        ((unsigned short*)res)[(size_t)row * 512 + (col - 512)] = f2b(gelu_exact(v));
                }
            }
        }
    }
}

// ---------------------------------------------------------------------------
// conv2 as GEMM with FUSED im2col staging (reg-staged: needs boundary zeros).
__global__ __launch_bounds__(256) void gemm_conv2(
    const unsigned short* __restrict__ h1, const unsigned short* __restrict__ Bt,
    const float* __restrict__ bias, float* __restrict__ Cout)
{
    __shared__ unsigned short As[128 * 64];
    __shared__ unsigned short Bs[128 * 64];
    int bm = blockIdx.x >> 1, bn = blockIdx.x & 1;
    int t = threadIdx.x, l = t & 63, w = t >> 6;
    int wm = w & 1, wn = w >> 1;
    f32x4 acc[4][4] = {};
    for (int kt = 0; kt < 12; ++kt) {
        int tpos = kt >> 2;
        int cbase = (kt & 3) * 64;
#pragma unroll
        for (int i = 0; i < 4; ++i) {
            int off = (i * 256 + t) * 8;
            int row = off >> 6, col = off & 63;
            int m = bm * 128 + row;
            int b = m / 400, ll = m % 400;
            int lp = ll + tpos - 1;
            ushort8 va = (ushort8)0;
            if (lp >= 0 && lp < 400)
                va = *(const ushort8*)(h1 + ((size_t)(b * 400 + lp) * 256 + cbase + col));
            *(ushort8*)(As + swz(off)) = va;
            ushort8 vb = *(const ushort8*)(Bt + (size_t)(bn * 128 + row) * 768 + kt * 64 + col);
            *(ushort8*)(Bs + swz(off)) = vb;
        }
        __syncthreads();
#pragma unroll
        for (int kk = 0; kk < 2; ++kk) {
            bf16x8 af[4], bfr[4];
#pragma unroll
            for (int i = 0; i < 4; ++i) {
                af[i]  = *(const bf16x8*)(As + swz((wm * 64 + i * 16 + (l & 15)) * 64 + kk * 32 + (l >> 4) * 8));
                bfr[i] = *(const bf16x8*)(Bs + swz((wn * 64 + i * 16 + (l & 15)) * 64 + kk * 32 + (l >> 4) * 8));
            }
#pragma unroll
            for (int i = 0; i < 4; ++i)
#pragma unroll
                for (int j = 0; j < 4; ++j)
                    acc[i][j] = __builtin_amdgcn_mfma_f32_16x16x32_bf16(af[i], bfr[j], acc[i][j], 0, 0, 0);
        }
        __syncthreads();
    }
    int r0 = bm * 128 + wm * 64 + (l >> 4) * 4;
    int c0 = bn * 128 + wn * 64 + (l & 15);
#pragma unroll
    for (int i = 0; i < 4; ++i)
#pragma unroll
        for (int j = 0; j < 4; ++j) {
            int col = c0 + j * 16;
            float bb = bias[col];
#pragma unroll
            for (int q = 0; q < 4; ++q) {
                int row = r0 + i * 16 + q;
                Cout[(size_t)row * 256 + col] = fmaxf(acc[i][j][q] + bb, 0.0f);
            }
        }
}

// ---------------------------------------------------------------------------
// depthwise conv (k=3, pad=1) + GELU; bf16 in/out; register-sliding window.
// 2048 blocks (25 positions each, 8 blocks/CU) + one-iteration-ahead prefetch:
// r3 (for step q+1) is issued before computing with r2, hiding HBM latency.
__global__ __launch_bounds__(256) void dwconv_kernel(
    const unsigned short* __restrict__ xp, const float* __restrict__ w,
    const float* __restrict__ bias, unsigned short* __restrict__ out)
{
    int b = blockIdx.x >> 4, tile = blockIdx.x & 15;
    int p0 = tile * 25;
    int t = threadIdx.x;
    int c = t * 2;
    float w00 = w[c * 3], w01 = w[c * 3 + 1], w02 = w[c * 3 + 2];
    float w10 = w[c * 3 + 3], w11 = w[c * 3 + 4], w12 = w[c * 3 + 5];
    float b0 = bias[c], b1 = bias[c + 1];
    const size_t rowb = (size_t)b * 400;
    int l = p0;
    unsigned int r0 = (l - 1 >= 0) ? *(const unsigned int*)(xp + (rowb + l - 1) * 512 + c) : 0u;
    unsigned int r1 = *(const unsigned int*)(xp + (rowb + l) * 512 + c);
    unsigned int r2 = (l + 1 < 400) ? *(const unsigned int*)(xp + (rowb + l + 1) * 512 + c) : 0u;
    for (int q = 0; q < 25; ++q, ++l) {
        unsigned int r3 = (l + 2 < 400) ? *(const unsigned int*)(xp + (rowb + l + 2) * 512 + c) : 0u;
        float a0 = b0 + b2f((unsigned short)(r0 & 0xffff)) * w00
                      + b2f((unsigned short)(r1 & 0xffff)) * w01
                      + b2f((unsigned short)(r2 & 0xffff)) * w02;
        float a1 = b1 + b2f((unsigned short)(r0 >> 16)) * w10
                      + b2f((unsigned short)(r1 >> 16)) * w11
                      + b2f((unsigned short)(r2 >> 16)) * w12;
        unsigned int o = (unsigned int)f2b(gelu_exact(a0)) | ((unsigned int)f2b(gelu_exact(a1)) << 16);
        *(unsigned int*)(out + (rowb + l) * 512 + c) = o;
        r0 = r1; r1 = r2; r2 = r3;
    }
}

// ---------------------------------------------------------------------------
// xproj as MFMA GEMM: BC(M x 32) = tanh(xcv(M x 512) @ W^T(32x512) + b).
__global__ __launch_bounds__(256) void xproj_mfma(
    const unsigned short* __restrict__ xc, const unsigned short* __restrict__ w,
    const float* __restrict__ bias, float* __restrict__ BC)
{
    __shared__ unsigned short As[128 * 64];
    __shared__ unsigned short Bs[32 * 64];
    int bm = blockIdx.x;
    int t = threadIdx.x, l = t & 63, wv = t >> 6;
    f32x4 acc[2][2] = {};
    for (int kt = 0; kt < 8; ++kt) {
#pragma unroll
        for (int i = 0; i < 4; ++i) {
            int off = (i * 256 + t) * 8;
            int row = off >> 6, col = off & 63;
            ushort8 va = *(const ushort8*)(xc + (size_t)(bm * 128 + row) * 512 + kt * 64 + col);
            *(ushort8*)(As + swz(off)) = va;
        }
        {
            int off = t * 8;
            int row = off >> 6, col = off & 63;
            ushort8 vb = *(const ushort8*)(w + (size_t)row * 512 + kt * 64 + col);
            *(ushort8*)(Bs + swz(off)) = vb;
        }
        __syncthreads();
#pragma unroll
        for (int kk = 0; kk < 2; ++kk) {
            bf16x8 af[2], bfr[2];
#pragma unroll
            for (int i = 0; i < 2; ++i) {
                af[i]  = *(const bf16x8*)(As + swz((wv * 32 + i * 16 + (l & 15)) * 64 + kk * 32 + (l >> 4) * 8));
                bfr[i] = *(const bf16x8*)(Bs + swz((i * 16 + (l & 15)) * 64 + kk * 32 + (l >> 4) * 8));
            }
#pragma unroll
            for (int i = 0; i < 2; ++i)
#pragma unroll
                for (int j = 0; j < 2; ++j)
                    acc[i][j] = __builtin_amdgcn_mfma_f32_16x16x32_bf16(af[i], bfr[j], acc[i][j], 0, 0, 0);
        }
        __syncthreads();
    }
    int r0 = bm * 128 + wv * 32 + (l >> 4) * 4;
    int c0 = l & 15;
#pragma unroll
    for (int i = 0; i < 2; ++i)
#pragma unroll
        for (int j = 0; j < 2; ++j) {
            int col = c0 + j * 16;
            float bb = bias[col];
#pragma unroll
            for (int q = 0; q < 4; ++q) {
                int row = r0 + i * 16 + q;
                BC[(size_t)row * 32 + col] = tanhf(acc[i][j][q] + bb);
            }
        }
}

// ---------------------------------------------------------------------------
// Sequential SSM scan. 256 threads (4 waves), 2 channels/thread (32 states).
// 50 chunks x 8 unrolled phases, register-resident operands, counted-lgkmcnt
// pre-barrier prefetch. (round-11 structure — best measured: ~265 us)
__global__ __launch_bounds__(256) void scan_kernel(
    const float* __restrict__ BC, const unsigned short* __restrict__ xconv,
    const unsigned short* __restrict__ gres, const float* __restrict__ Aw,
    const float* __restrict__ Dw, const float* __restrict__ sng,
    const float* __restrict__ snb, unsigned short* __restrict__ yg)
{
    __shared__ __align__(16) unsigned short lds_x[2][4096];
    __shared__ __align__(16) unsigned short lds_g[2][4096];
    __shared__ __align__(16) float lds_bc[2][256];
    __shared__ __align__(16) float lds_s1[2][4];
    __shared__ __align__(16) float lds_s2[2][4];
    int b = blockIdx.x, t = threadIdx.x;
    int d0 = t * 2;
    f32x2 st2[16], tA2[16], g2[16], bb2[16];
#pragma unroll
    for (int ch = 0; ch < 2; ++ch)
#pragma unroll
        for (int j = 0; j < 8; ++j) {
            int idx = ch * 8 + j;
            st2[idx] = (f32x2)(0.0f);
            f32x2 av = *(const f32x2*)(Aw + (d0 + ch) * 16 + j * 2);
            tA2[idx] = (f32x2){tanhf(av.x), tanhf(av.y)};
            g2[idx]  = *(const f32x2*)(sng + (d0 + ch) * 16 + j * 2);
            bb2[idx] = *(const f32x2*)(snb + (d0 + ch) * 16 + j * 2);
        }
    f32x2 Dd = *(const f32x2*)(Dw + d0);
    const size_t base = (size_t)b * 400;
    {
        size_t o = base * 512 + t * 16;
        *(ushort8*)(&lds_x[0][t * 16])     = *(const ushort8*)(xconv + o);
        *(ushort8*)(&lds_x[0][t * 16 + 8]) = *(const ushort8*)(xconv + o + 8);
        *(ushort8*)(&lds_g[0][t * 16])     = *(const ushort8*)(gres + o);
        *(ushort8*)(&lds_g[0][t * 16 + 8]) = *(const ushort8*)(gres + o + 8);
        if (t < 64) *(float4*)(&lds_bc[0][t * 4]) = *(const float4*)(BC + base * 32 + t * 4);
    }
    bar_lgkm();
    float4 bcv[8];
#pragma unroll
    for (int q = 0; q < 8; ++q) bcv[q] = *(const float4*)&lds_bc[0][q * 4];
    unsigned int cxr = *(const unsigned int*)&lds_x[0][d0];
    unsigned int cgr = *(const unsigned int*)&lds_g[0][d0];
    ushort8 xr0, xr1, gr0, gr1; float4 bc_r;
    for (int c = 0; c < 50; ++c) {
        int cur = c & 1;
        const size_t lbase = base + c * 8;
#pragma unroll
        for (int pp = 0; pp < 8; ++pp) {
            if (pp == 0 && c + 1 < 50) {
                size_t o = (lbase + 8) * 512 + t * 16;
                xr0 = *(const ushort8*)(xconv + o);
                xr1 = *(const ushort8*)(xconv + o + 8);
                gr0 = *(const ushort8*)(gres + o);
                gr1 = *(const ushort8*)(gres + o + 8);
                if (t < 64) bc_r = *(const float4*)(BC + (lbase + 8) * 32 + t * 4);
            }
            const f32x2* Bp = (const f32x2*)&bcv[0];
            const f32x2* Cp = (const f32x2*)&bcv[4];
            float x0 = b2f((unsigned short)(cxr & 0xffff)), x1 = b2f((unsigned short)(cxr >> 16));
            float ga0 = b2f((unsigned short)(cgr & 0xffff)), ga1 = b2f((unsigned short)(cgr >> 16));
            f32x2 o0A = (f32x2){x0 * Dd.x, 0.0f}, o0B = (f32x2)(0.0f);
            f32x2 o1A = (f32x2){x1 * Dd.y, 0.0f}, o1B = (f32x2)(0.0f);
#pragma unroll
            for (int j = 0; j < 8; j += 2) {
                st2[j]     = pk_add(st2[j],     Bp[j]);     o0A = pk_fma(st2[j],     Cp[j],     o0A);
                st2[j + 1] = pk_add(st2[j + 1], Bp[j + 1]); o0B = pk_fma(st2[j + 1], Cp[j + 1], o0B);
                st2[8 + j]     = pk_add(st2[8 + j],     Bp[j]);     o1A = pk_fma(st2[8 + j],     Cp[j],     o1A);
                st2[8 + j + 1] = pk_add(st2[8 + j + 1], Bp[j + 1]); o1B = pk_fma(st2[8 + j + 1], Cp[j + 1], o1B);
            }
            f32x2 o0 = pk_add(o0A, o0B), o1 = pk_add(o1A, o1B);
            unsigned int oy = (unsigned int)f2b((o0.x + o0.y) * ga0)
                            | ((unsigned int)f2b((o1.x + o1.y) * ga1) << 16);
            *(unsigned int*)(yg + (lbase + pp) * 512 + d0) = oy;
            f32x2 sA = (f32x2)(0.0f), sB = (f32x2)(0.0f), sC = (f32x2)(0.0f), sD = (f32x2)(0.0f);
            f32x2 qA = (f32x2)(0.0f), qB = (f32x2)(0.0f), qC = (f32x2)(0.0f), qD = (f32x2)(0.0f);
#pragma unroll
            for (int j = 0; j < 16; j += 4) {
                st2[j]     = pk_mul(st2[j],     tA2[j]);     sA = pk_add(sA, st2[j]);     qA = pk_fma(st2[j],     st2[j],     qA);
                st2[j + 1] = pk_mul(st2[j + 1], tA2[j + 1]); sB = pk_add(sB, st2[j + 1]); qB = pk_fma(st2[j + 1], st2[j + 1], qB);
                st2[j + 2] = pk_mul(st2[j + 2], tA2[j + 2]); sC = pk_add(sC, st2[j + 2]); qC = pk_fma(st2[j + 2], st2[j + 2], qC);
                st2[j + 3] = pk_mul(st2[j + 3], tA2[j + 3]); sD = pk_add(sD, st2[j + 3]); qD = pk_fma(st2[j + 3], st2[j + 3], qD);
            }
            f32x2 sS = pk_add(pk_add(sA, sB), pk_add(sC, sD));
            f32x2 qS = pk_add(pk_add(qA, qB), pk_add(qC, qD));
            float s1 = wave_sum63(sS.x + sS.y);
            float s2 = wave_sum63(qS.x + qS.y);
            if (pp == 6 && c + 1 < 50) {
                if (t < 64) *(float4*)(&lds_bc[cur ^ 1][t * 4]) = bc_r;
            }
            if (pp == 7 && c + 1 < 50) {
                *(ushort8*)(&lds_x[cur ^ 1][t * 16])     = xr0;
                *(ushort8*)(&lds_x[cur ^ 1][t * 16 + 8]) = xr1;
                *(ushort8*)(&lds_g[cur ^ 1][t * 16])     = gr0;
                *(ushort8*)(&lds_g[cur ^ 1][t * 16 + 8]) = gr1;
            }
            if ((t & 63) == 63) { lds_s1[pp & 1][t >> 6] = s1; lds_s2[pp & 1][t >> 6] = s2; }
            __builtin_amdgcn_sched_barrier(0);
            float4 nbc[8]; unsigned int nxr = 0, ngr = 0;
            if (pp < 7) {
#pragma unroll
                for (int q = 0; q < 8; ++q)
                    nbc[q] = *(const float4*)&lds_bc[cur][(pp + 1) * 32 + q * 4];
                nxr = *(const unsigned int*)&lds_x[cur][(pp + 1) * 512 + d0];
                ngr = *(const unsigned int*)&lds_g[cur][(pp + 1) * 512 + d0];
                __builtin_amdgcn_sched_barrier(0);
                asm volatile("s_waitcnt lgkmcnt(10)" ::: "memory");
            } else if (c + 1 < 50) {
#pragma unroll
                for (int q = 0; q < 8; ++q)
                    nbc[q] = *(const float4*)&lds_bc[cur ^ 1][q * 4];
                __builtin_amdgcn_sched_barrier(0);
                asm volatile("s_waitcnt lgkmcnt(8)" ::: "memory");
            } else {
                asm volatile("s_waitcnt lgkmcnt(0)" ::: "memory");
            }
            __builtin_amdgcn_s_barrier();
            __builtin_amdgcn_sched_barrier(0);
            float4 p0v = *(const float4*)&lds_s1[pp & 1][0];
            float4 r0v = *(const float4*)&lds_s2[pp & 1][0];
            float S1 = (p0v.x + p0v.y) + (p0v.z + p0v.w);
            float S2 = (r0v.x + r0v.y) + (r0v.z + r0v.w);
            float mu = S1 * (1.0f / 8192.0f);
            float var = S2 * (1.0f / 8192.0f) - mu * mu;
            float rs = rsqrtf(var + 1e-5f);
            f32x2 rs2 = (f32x2){rs, rs};
            f32x2 nm2 = (f32x2){-mu * rs, -mu * rs};
#pragma unroll
            for (int j = 0; j < 16; ++j) {
                f32x2 zn = pk_fma(st2[j], rs2, nm2);
                st2[j] = pk_fma(zn, g2[j], bb2[j]);
            }
            if (pp < 7) {
#pragma unroll
                for (int q = 0; q < 8; ++q) bcv[q] = nbc[q];
                cxr = nxr; cgr = ngr;
            } else if (c + 1 < 50) {
#pragma unroll
                for (int q = 0; q < 8; ++q) bcv[q] = nbc[q];
                cxr = *(const unsigned int*)&lds_x[cur ^ 1][d0];
                cgr = *(const unsigned int*)&lds_g[cur ^ 1][d0];
            }
        }
    }
}

// ---------------------------------------------------------------------------
// pooling stage A: partial sums over 50-position segments.
// grid = 128 batches x 8 segments; thread = channel.
__global__ __launch_bounds__(256) void pool_partial_kernel(
    const float* __restrict__ h, float* __restrict__ part)
{
    int b = blockIdx.x >> 3, seg = blockIdx.x & 7;
    int t = threadIdx.x;
    const float* p = h + ((size_t)b * 400 + seg * 50) * 256 + t;
    float s = 0.0f;
#pragma unroll 5
    for (int l = 0; l < 50; ++l) s += p[(size_t)l * 256];
    part[((size_t)b * 8 + seg) * 256 + t] = s;
}

// pooling stage B: reduce 8 partials + FC (37 classes). 1 block per batch.
__global__ __launch_bounds__(256) void poolfc_kernel(
    const float* __restrict__ part, const float* __restrict__ fcw,
    const float* __restrict__ fcb, float* __restrict__ out)
{
    __shared__ float ps[256];
    int b = blockIdx.x, t = threadIdx.x;
    float s = 0.0f;
#pragma unroll
    for (int seg = 0; seg < 8; ++seg) s += part[((size_t)b * 8 + seg) * 256 + t];
    ps[t] = s * (1.0f / 400.0f);
    __syncthreads();
    if (t < 37) {
        float acc = fcb[t];
        for (int o = 0; o < 256; ++o) acc += ps[o] * fcw[t * 256 + o];
        out[b * 37 + t] = acc;
    }
}

// ---------------------------------------------------------------------------
extern "C" void kernel_launch(void* const* d_in, const int* in_sizes, int n_in,
                              void* d_out, int out_size, void* d_ws, size_t ws_size,
                              hipStream_t stream)
{
    const float* x         = (const float*)d_in[0];
    const float* conv1_w   = (const float*)d_in[1];
    const float* conv1_b   = (const float*)d_in[2];
    const float* conv2_w   = (const float*)d_in[3];
    const float* conv2_b   = (const float*)d_in[4];
    const float* ln_g      = (const float*)d_in[5];
    const float* ln_b      = (const float*)d_in[6];
    const float* inproj_w  = (const float*)d_in[7];
    const float* inproj_b  = (const float*)d_in[8];
    const float* dw_w      = (const float*)d_in[9];
    const float* dw_b      = (const float*)d_in[10];
    const float* xproj_w   = (const float*)d_in[11];
    const float* xproj_b   = (const float*)d_in[12];
    const float* A         = (const float*)d_in[13];
    const float* D         = (const float*)d_in[14];
    const float* sn_g      = (const float*)d_in[15];
    const float* sn_b      = (const float*)d_in[16];
    const float* outproj_w = (const float*)d_in[17];
    const float* outproj_b = (const float*)d_in[18];
    const float* fc_w      = (const float*)d_in[19];
    const float* fc_b      = (const float*)d_in[20];
    float* out = (float*)d_out;

    const int M = 51200; // B*L

    // Workspace: big buffers (243,007,488) + weights (2,031,616) + pool partials (1,048,576)
    if (ws_size < 245563392u) return;
    char* ws = (char*)d_ws;
    float*          h    = (float*)(ws);
    unsigned short* hn   = (unsigned short*)(ws + 52428800);
    unsigned short* h1   = (unsigned short*)(ws + 52428800);
    unsigned short* xp_c = (unsigned short*)(ws + 78643200);
    unsigned short* yg   = (unsigned short*)(ws + 78643200);
    unsigned short* grs  = (unsigned short*)(ws + 131072000);
    unsigned short* xcv  = (unsigned short*)(ws + 183500800);
    float*          BC   = (float*)(ws + 235929600);
    unsigned short* wb   = (unsigned short*)(ws + 242483200);
    unsigned short* w2r   = wb;
    unsigned short* winp0 = wb + 196608;
    unsigned short* winp1 = wb + 458752;
    unsigned short* wxp0  = wb + 720896;
    unsigned short* wxp1  = wb + 737280;
    unsigned short* wout0 = wb + 753664;
    unsigned short* wout1 = wb + 884736;
    float*          part  = (float*)(ws + 244514816);   // 128*8*256 fp32 = 1 MB
    unsigned short* winp[2] = {winp0, winp1};
    unsigned short* wxp[2]  = {wxp0, wxp1};
    unsigned short* wout[2] = {wout0, wout1};

    // --- hoisted weight prep ---
    reorder_w2_kernel<<<768, 256, 0, stream>>>(conv2_w, w2r);
    for (int i = 0; i < 2; ++i) {
        castw_kernel<<<1024, 256, 0, stream>>>(inproj_w + (size_t)i * 262144, winp[i], 262144);
        castw_kernel<<<64, 256, 0, stream>>>(xproj_w + i * 16384, wxp[i], 16384);
        castw_kernel<<<512, 256, 0, stream>>>(outproj_w + (size_t)i * 131072, wout[i], 131072);
    }

    conv1_kernel<<<128 * 8, 256, 0, stream>>>(x, conv1_w, conv1_b, h1);
    gemm_conv2<<<(M / 128) * 2, 256, 0, stream>>>(h1, w2r, conv2_b, h);

    for (int i = 0; i < 2; ++i) {
        ln_kernel<<<M / 4, 256, 0, stream>>>(h, ln_g + i * 256, ln_b + i * 256, hn);
        gemm_bt<4><<<(M / 128) * 8, 256, 0, stream>>>(hn, winp[i], inproj_b + i * 1024,
                                                      (const float*)grs, xp_c, 1024, 256, 256, 512);
        dwconv_kernel<<<2048, 256, 0, stream>>>(xp_c, dw_w + i * 1536, dw_b + i * 512, xcv);
        xproj_mfma<<<M / 128, 256, 0, stream>>>(xcv, wxp[i], xproj_b + i * 32, BC);
        scan_kernel<<<128, 256, 0, stream>>>(BC, xcv, grs, A + i * 8192, D + i * 512,
                                             sn_g + i * 8192, sn_b + i * 8192, yg);
        gemm_bt<3><<<(M / 128) * 2, 256, 0, stream>>>(yg, wout[i], outproj_b + i * 256, h, h,
                                                      256, 512, 512, 256);
    }
    pool_partial_kernel<<<128 * 8, 256, 0, stream>>>(h, part);
    poolfc_kernel<<<128, 256, 0, stream>>>(part, fc_w, fc_b, out);
}

// Round 15
// 922.913 us; speedup vs baseline: 1.3041x; 1.0163x over previous
//
#include <hip/hip_runtime.h>
#include <hip/hip_bf16.h>
#include <math.h>

#define DEVINL __device__ __forceinline__

typedef __attribute__((ext_vector_type(2))) float  f32x2;
typedef __attribute__((ext_vector_type(4))) float  f32x4;
typedef __attribute__((ext_vector_type(8))) __bf16 bf16x8;
typedef __attribute__((ext_vector_type(8))) unsigned short ushort8;

DEVINL float b2f(unsigned short u) {
    union { unsigned int i; float f; } v; v.i = ((unsigned int)u) << 16; return v.f;
}
DEVINL unsigned short f2b(float f) {
    union { float f; unsigned int i; } v; v.f = f;
    unsigned int u = v.i;
    unsigned int r = (u + 0x7fffu + ((u >> 16) & 1u)) >> 16;
    return (unsigned short)r;
}
DEVINL float gelu_exact(float x) {
    return 0.5f * x * (1.0f + erff(x * 0.70710678118654752440f));
}

// VOP3P packed fp32 (CDNA2+): 2 FLOPs per instruction on register pairs.
DEVINL f32x2 pk_fma(f32x2 a, f32x2 b, f32x2 c) {
    f32x2 d; asm("v_pk_fma_f32 %0, %1, %2, %3" : "=v"(d) : "v"(a), "v"(b), "v"(c)); return d;
}
DEVINL f32x2 pk_add(f32x2 a, f32x2 b) {
    f32x2 d; asm("v_pk_add_f32 %0, %1, %2" : "=v"(d) : "v"(a), "v"(b)); return d;
}
DEVINL f32x2 pk_mul(f32x2 a, f32x2 b) {
    f32x2 d; asm("v_pk_mul_f32 %0, %1, %2" : "=v"(d) : "v"(a), "v"(b)); return d;
}

// Barrier that drains ONLY LDS (lgkmcnt).
DEVINL void bar_lgkm() {
    asm volatile("s_waitcnt lgkmcnt(0)" ::: "memory");
    __builtin_amdgcn_s_barrier();
    __builtin_amdgcn_sched_barrier(0);
}

// LDS XOR swizzle (T2): permute 8-element groups within a 64-elem row by row&7.
DEVINL int swz(int off) { return off ^ (((off >> 6) & 7) << 3); }

// Direct global->LDS async copy, 16B per lane (linear LDS dest, pre-swizzled src).
DEVINL void gload16(const unsigned short* g, unsigned short* l) {
    __builtin_amdgcn_global_load_lds(
        (const __attribute__((address_space(1))) unsigned int*)g,
        (__attribute__((address_space(3))) unsigned int*)l, 16, 0, 0);
}

// DPP-based wave64 sum: result valid in lane 63 of each wave.
template <int CTRL>
DEVINL float dpp_add(float x) {
    int xi = __builtin_bit_cast(int, x);
    int yi = __builtin_amdgcn_update_dpp(0, xi, CTRL, 0xf, 0xf, true);
    return x + __builtin_bit_cast(float, yi);
}
DEVINL float wave_sum63(float x) {
    x = dpp_add<0x111>(x);
    x = dpp_add<0x112>(x);
    x = dpp_add<0x114>(x);
    x = dpp_add<0x118>(x);
    x = dpp_add<0x142>(x);
    x = dpp_add<0x143>(x);
    return x;
}

// ---------------------------------------------------------------------------
// conv1 (Cin=8 -> 256, k=3, pad=1) + ReLU, output bf16.
__global__ __launch_bounds__(256) void conv1_kernel(
    const float* __restrict__ x, const float* __restrict__ w,
    const float* __restrict__ bias, unsigned short* __restrict__ h1)
{
    __shared__ float xs[52 * 8];
    int b = blockIdx.x >> 3, tile = blockIdx.x & 7;
    int p0 = tile * 50;
    int t = threadIdx.x;
    for (int i = t; i < 416; i += 256) {
        int p = i >> 3, c = i & 7;
        int lp = p0 + p - 1;
        xs[i] = (lp >= 0 && lp < 400) ? x[((size_t)b * 400 + lp) * 8 + c] : 0.0f;
    }
    float wr[24];
    const float4* wp = (const float4*)(w + t * 24);
#pragma unroll
    for (int i = 0; i < 6; ++i) {
        float4 v4 = wp[i];
        wr[i * 4] = v4.x; wr[i * 4 + 1] = v4.y; wr[i * 4 + 2] = v4.z; wr[i * 4 + 3] = v4.w;
    }
    float bs = bias[t];
    __syncthreads();
#pragma unroll 2
    for (int p = 0; p < 50; ++p) {
        float acc = bs;
#pragma unroll
        for (int dt = 0; dt < 3; ++dt)
#pragma unroll
            for (int c = 0; c < 8; ++c)
                acc += xs[(p + dt) * 8 + c] * wr[c * 3 + dt];
        h1[((size_t)b * 400 + p0 + p) * 256 + t] = f2b(fmaxf(acc, 0.0f));
    }
}

// ---------------------------------------------------------------------------
// Single fused weight-prep kernel: fills the whole wb area (contiguous layout:
// w2r | winp0 | winp1 | wxp0 | wxp1 | wout0 | wout1 = 1,015,808 bf16 elems).
__global__ void prep_weights_kernel(
    const float* __restrict__ conv2_w, const float* __restrict__ inproj_w,
    const float* __restrict__ xproj_w, const float* __restrict__ outproj_w,
    unsigned short* __restrict__ wb)
{
    int idx = blockIdx.x * 256 + threadIdx.x;
    if (idx >= 1015808) return;
    float v;
    if (idx < 196608) {                      // conv2 reorder (o, ci, t) -> [o, t*256+ci]
        int o = idx / 768, r = idx % 768;
        int tpos = r / 256, ci = r % 256;
        v = conv2_w[o * 768 + ci * 3 + tpos];
    } else if (idx < 720896) {               // inproj (both layers, contiguous)
        v = inproj_w[idx - 196608];
    } else if (idx < 753664) {               // xproj
        v = xproj_w[idx - 720896];
    } else {                                 // outproj
        v = outproj_w[idx - 753664];
    }
    wb[idx] = f2b(v);
}

// ---------------------------------------------------------------------------
// LayerNorm over dm=256 per row, fp32 in -> bf16 out. 4 rows/block (1/wave).
__global__ __launch_bounds__(256) void ln_kernel(
    const float* __restrict__ h, const float* __restrict__ g,
    const float* __restrict__ bta, unsigned short* __restrict__ out)
{
    int w = threadIdx.x >> 6, l = threadIdx.x & 63;
    int row = blockIdx.x * 4 + w;
    const float* p = h + (size_t)row * 256 + l * 4;
    float4 v = *(const float4*)p;
    float s  = v.x + v.y + v.z + v.w;
    float s2 = v.x * v.x + v.y * v.y + v.z * v.z + v.w * v.w;
#pragma unroll
    for (int m = 1; m < 64; m <<= 1) { s += __shfl_xor(s, m); s2 += __shfl_xor(s2, m); }
    float mu = s * (1.0f / 256.0f);
    float var = s2 * (1.0f / 256.0f) - mu * mu;
    float rs = rsqrtf(var + 1e-5f);
    float4 gg = *(const float4*)(g + l * 4);
    float4 bb = *(const float4*)(bta + l * 4);
    ushort4 o;
    o.x = f2b((v.x - mu) * rs * gg.x + bb.x);
    o.y = f2b((v.y - mu) * rs * gg.y + bb.y);
    o.z = f2b((v.z - mu) * rs * gg.z + bb.z);
    o.w = f2b((v.w - mu) * rs * gg.w + bb.w);
    *(ushort4*)(out + (size_t)row * 256 + l * 4) = o;
}

// ---------------------------------------------------------------------------
// bf16 GEMM, 128x128 tile: C(MxN) = A(MxK, lda) * Bt(NxK)^T.
// Staging: global_load_lds (16B/lane, linear LDS dest) with pre-swizzled source.
// EPI 0: +bias bf16.  1: +bias GELU bf16.  3: +bias+res fp32.
// EPI 4 (fused inproj): col<512 -> plain bf16; col>=512 -> GELU bf16 to res.
template <int EPI>
__global__ __launch_bounds__(256) void gemm_bt(
    const unsigned short* __restrict__ A, const unsigned short* __restrict__ Bt,
    const float* __restrict__ bias, const float* __restrict__ res,
    void* __restrict__ Cout, int N, int K, int lda, int ldc)
{
    __shared__ unsigned short As[128 * 64];
    __shared__ unsigned short Bs[128 * 64];
    const int nbn = N >> 7;
    int bm = blockIdx.x / nbn, bn = blockIdx.x % nbn;
    int t = threadIdx.x, l = t & 63, w = t >> 6;
    int wm = w & 1, wn = w >> 1;
    int srow = t >> 3;
    int scol = 8 * ((t & 7) ^ ((t >> 3) & 7));
    f32x4 acc[4][4] = {};
    const int ktn = K >> 6;
    for (int kt = 0; kt < ktn; ++kt) {
#pragma unroll
        for (int i = 0; i < 4; ++i) {
            int row = i * 32 + srow;
            gload16(A + (size_t)(bm * 128 + row) * lda + kt * 64 + scol,
                    As + (i * 256 + w * 64) * 8);
            gload16(Bt + (size_t)(bn * 128 + row) * K + kt * 64 + scol,
                    Bs + (i * 256 + w * 64) * 8);
        }
        __syncthreads();
#pragma unroll
        for (int kk = 0; kk < 2; ++kk) {
            bf16x8 af[4], bfr[4];
#pragma unroll
            for (int i = 0; i < 4; ++i) {
                af[i]  = *(const bf16x8*)(As + swz((wm * 64 + i * 16 + (l & 15)) * 64 + kk * 32 + (l >> 4) * 8));
                bfr[i] = *(const bf16x8*)(Bs + swz((wn * 64 + i * 16 + (l & 15)) * 64 + kk * 32 + (l >> 4) * 8));
            }
#pragma unroll
            for (int i = 0; i < 4; ++i)
#pragma unroll
                for (int j = 0; j < 4; ++j)
                    acc[i][j] = __builtin_amdgcn_mfma_f32_16x16x32_bf16(af[i], bfr[j], acc[i][j], 0, 0, 0);
        }
        __syncthreads();
    }
    int r0 = bm * 128 + wm * 64 + (l >> 4) * 4;
    int c0 = bn * 128 + wn * 64 + (l & 15);
#pragma unroll
    for (int i = 0; i < 4; ++i) {
#pragma unroll
        for (int j = 0; j < 4; ++j) {
            int col = c0 + j * 16;
            float bb = bias[col];
#pragma unroll
            for (int q = 0; q < 4; ++q) {
                int row = r0 + i * 16 + q;
                float v = acc[i][j][q] + bb;
                if (EPI == 0) {
                    ((unsigned short*)Cout)[(size_t)row * ldc + col] = f2b(v);
                } else if (EPI == 1) {
                    ((unsigned short*)Cout)[(size_t)row * ldc + col] = f2b(gelu_exact(v));
                } else if (EPI == 3) {
                    size_t idx = (size_t)row * ldc + col;
                    ((float*)Cout)[idx] = v + res[idx];
                } else {    // EPI 4: fused inproj split epilogue
                    if (col < 512)
                        ((unsigned short*)Cout)[(size_t)row * 512 + col] = f2b(v);
                    else
                        ((unsigned short*)res)[(size_t)row * 512 + (col - 512)] = f2b(gelu_exact(v));
                }
            }
        }
    }
}

// ---------------------------------------------------------------------------
// conv2 as GEMM with FUSED im2col staging (reg-staged: needs boundary zeros).
__global__ __launch_bounds__(256) void gemm_conv2(
    const unsigned short* __restrict__ h1, const unsigned short* __restrict__ Bt,
    const float* __restrict__ bias, float* __restrict__ Cout)
{
    __shared__ unsigned short As[128 * 64];
    __shared__ unsigned short Bs[128 * 64];
    int bm = blockIdx.x >> 1, bn = blockIdx.x & 1;
    int t = threadIdx.x, l = t & 63, w = t >> 6;
    int wm = w & 1, wn = w >> 1;
    f32x4 acc[4][4] = {};
    for (int kt = 0; kt < 12; ++kt) {
        int tpos = kt >> 2;
        int cbase = (kt & 3) * 64;
#pragma unroll
        for (int i = 0; i < 4; ++i) {
            int off = (i * 256 + t) * 8;
            int row = off >> 6, col = off & 63;
            int m = bm * 128 + row;
            int b = m / 400, ll = m % 400;
            int lp = ll + tpos - 1;
            ushort8 va = (ushort8)0;
            if (lp >= 0 && lp < 400)
                va = *(const ushort8*)(h1 + ((size_t)(b * 400 + lp) * 256 + cbase + col));
            *(ushort8*)(As + swz(off)) = va;
            ushort8 vb = *(const ushort8*)(Bt + (size_t)(bn * 128 + row) * 768 + kt * 64 + col);
            *(ushort8*)(Bs + swz(off)) = vb;
        }
        __syncthreads();
#pragma unroll
        for (int kk = 0; kk < 2; ++kk) {
            bf16x8 af[4], bfr[4];
#pragma unroll
            for (int i = 0; i < 4; ++i) {
                af[i]  = *(const bf16x8*)(As + swz((wm * 64 + i * 16 + (l & 15)) * 64 + kk * 32 + (l >> 4) * 8));
                bfr[i] = *(const bf16x8*)(Bs + swz((wn * 64 + i * 16 + (l & 15)) * 64 + kk * 32 + (l >> 4) * 8));
            }
#pragma unroll
            for (int i = 0; i < 4; ++i)
#pragma unroll
                for (int j = 0; j < 4; ++j)
                    acc[i][j] = __builtin_amdgcn_mfma_f32_16x16x32_bf16(af[i], bfr[j], acc[i][j], 0, 0, 0);
        }
        __syncthreads();
    }
    int r0 = bm * 128 + wm * 64 + (l >> 4) * 4;
    int c0 = bn * 128 + wn * 64 + (l & 15);
#pragma unroll
    for (int i = 0; i < 4; ++i)
#pragma unroll
        for (int j = 0; j < 4; ++j) {
            int col = c0 + j * 16;
            float bb = bias[col];
#pragma unroll
            for (int q = 0; q < 4; ++q) {
                int row = r0 + i * 16 + q;
                Cout[(size_t)row * 256 + col] = fmaxf(acc[i][j][q] + bb, 0.0f);
            }
        }
}

// ---------------------------------------------------------------------------
// depthwise conv (k=3, pad=1) + GELU; bf16 in/out; register-sliding window.
// 2048 blocks (25 positions each) + one-iteration-ahead prefetch.
__global__ __launch_bounds__(256) void dwconv_kernel(
    const unsigned short* __restrict__ xp, const float* __restrict__ w,
    const float* __restrict__ bias, unsigned short* __restrict__ out)
{
    int b = blockIdx.x >> 4, tile = blockIdx.x & 15;
    int p0 = tile * 25;
    int t = threadIdx.x;
    int c = t * 2;
    float w00 = w[c * 3], w01 = w[c * 3 + 1], w02 = w[c * 3 + 2];
    float w10 = w[c * 3 + 3], w11 = w[c * 3 + 4], w12 = w[c * 3 + 5];
    float b0 = bias[c], b1 = bias[c + 1];
    const size_t rowb = (size_t)b * 400;
    int l = p0;
    unsigned int r0 = (l - 1 >= 0) ? *(const unsigned int*)(xp + (rowb + l - 1) * 512 + c) : 0u;
    unsigned int r1 = *(const unsigned int*)(xp + (rowb + l) * 512 + c);
    unsigned int r2 = (l + 1 < 400) ? *(const unsigned int*)(xp + (rowb + l + 1) * 512 + c) : 0u;
    for (int q = 0; q < 25; ++q, ++l) {
        unsigned int r3 = (l + 2 < 400) ? *(const unsigned int*)(xp + (rowb + l + 2) * 512 + c) : 0u;
        float a0 = b0 + b2f((unsigned short)(r0 & 0xffff)) * w00
                      + b2f((unsigned short)(r1 & 0xffff)) * w01
                      + b2f((unsigned short)(r2 & 0xffff)) * w02;
        float a1 = b1 + b2f((unsigned short)(r0 >> 16)) * w10
                      + b2f((unsigned short)(r1 >> 16)) * w11
                      + b2f((unsigned short)(r2 >> 16)) * w12;
        unsigned int o = (unsigned int)f2b(gelu_exact(a0)) | ((unsigned int)f2b(gelu_exact(a1)) << 16);
        *(unsigned int*)(out + (rowb + l) * 512 + c) = o;
        r0 = r1; r1 = r2; r2 = r3;
    }
}

// ---------------------------------------------------------------------------
// xproj as MFMA GEMM: BC(M x 32) = tanh(xcv(M x 512) @ W^T(32x512) + b).
__global__ __launch_bounds__(256) void xproj_mfma(
    const unsigned short* __restrict__ xc, const unsigned short* __restrict__ w,
    const float* __restrict__ bias, float* __restrict__ BC)
{
    __shared__ unsigned short As[128 * 64];
    __shared__ unsigned short Bs[32 * 64];
    int bm = blockIdx.x;
    int t = threadIdx.x, l = t & 63, wv = t >> 6;
    f32x4 acc[2][2] = {};
    for (int kt = 0; kt < 8; ++kt) {
#pragma unroll
        for (int i = 0; i < 4; ++i) {
            int off = (i * 256 + t) * 8;
            int row = off >> 6, col = off & 63;
            ushort8 va = *(const ushort8*)(xc + (size_t)(bm * 128 + row) * 512 + kt * 64 + col);
            *(ushort8*)(As + swz(off)) = va;
        }
        {
            int off = t * 8;
            int row = off >> 6, col = off & 63;
            ushort8 vb = *(const ushort8*)(w + (size_t)row * 512 + kt * 64 + col);
            *(ushort8*)(Bs + swz(off)) = vb;
        }
        __syncthreads();
#pragma unroll
        for (int kk = 0; kk < 2; ++kk) {
            bf16x8 af[2], bfr[2];
#pragma unroll
            for (int i = 0; i < 2; ++i) {
                af[i]  = *(const bf16x8*)(As + swz((wv * 32 + i * 16 + (l & 15)) * 64 + kk * 32 + (l >> 4) * 8));
                bfr[i] = *(const bf16x8*)(Bs + swz((i * 16 + (l & 15)) * 64 + kk * 32 + (l >> 4) * 8));
            }
#pragma unroll
            for (int i = 0; i < 2; ++i)
#pragma unroll
                for (int j = 0; j < 2; ++j)
                    acc[i][j] = __builtin_amdgcn_mfma_f32_16x16x32_bf16(af[i], bfr[j], acc[i][j], 0, 0, 0);
        }
        __syncthreads();
    }
    int r0 = bm * 128 + wv * 32 + (l >> 4) * 4;
    int c0 = l & 15;
#pragma unroll
    for (int i = 0; i < 2; ++i)
#pragma unroll
        for (int j = 0; j < 2; ++j) {
            int col = c0 + j * 16;
            float bb = bias[col];
#pragma unroll
            for (int q = 0; q < 4; ++q) {
                int row = r0 + i * 16 + q;
                BC[(size_t)row * 32 + col] = tanhf(acc[i][j][q] + bb);
            }
        }
}

// ---------------------------------------------------------------------------
// Sequential SSM scan. 256 threads (4 waves), 2 channels/thread (32 states).
// 50 chunks x 8 unrolled phases, register-resident operands, counted-lgkmcnt
// pre-barrier prefetch. (best measured: ~265 us/dispatch — latency floor)
__global__ __launch_bounds__(256) void scan_kernel(
    const float* __restrict__ BC, const unsigned short* __restrict__ xconv,
    const unsigned short* __restrict__ gres, const float* __restrict__ Aw,
    const float* __restrict__ Dw, const float* __restrict__ sng,
    const float* __restrict__ snb, unsigned short* __restrict__ yg)
{
    __shared__ __align__(16) unsigned short lds_x[2][4096];
    __shared__ __align__(16) unsigned short lds_g[2][4096];
    __shared__ __align__(16) float lds_bc[2][256];
    __shared__ __align__(16) float lds_s1[2][4];
    __shared__ __align__(16) float lds_s2[2][4];
    int b = blockIdx.x, t = threadIdx.x;
    int d0 = t * 2;
    f32x2 st2[16], tA2[16], g2[16], bb2[16];
#pragma unroll
    for (int ch = 0; ch < 2; ++ch)
#pragma unroll
        for (int j = 0; j < 8; ++j) {
            int idx = ch * 8 + j;
            st2[idx] = (f32x2)(0.0f);
            f32x2 av = *(const f32x2*)(Aw + (d0 + ch) * 16 + j * 2);
            tA2[idx] = (f32x2){tanhf(av.x), tanhf(av.y)};
            g2[idx]  = *(const f32x2*)(sng + (d0 + ch) * 16 + j * 2);
            bb2[idx] = *(const f32x2*)(snb + (d0 + ch) * 16 + j * 2);
        }
    f32x2 Dd = *(const f32x2*)(Dw + d0);
    const size_t base = (size_t)b * 400;
    {
        size_t o = base * 512 + t * 16;
        *(ushort8*)(&lds_x[0][t * 16])     = *(const ushort8*)(xconv + o);
        *(ushort8*)(&lds_x[0][t * 16 + 8]) = *(const ushort8*)(xconv + o + 8);
        *(ushort8*)(&lds_g[0][t * 16])     = *(const ushort8*)(gres + o);
        *(ushort8*)(&lds_g[0][t * 16 + 8]) = *(const ushort8*)(gres + o + 8);
        if (t < 64) *(float4*)(&lds_bc[0][t * 4]) = *(const float4*)(BC + base * 32 + t * 4);
    }
    bar_lgkm();
    float4 bcv[8];
#pragma unroll
    for (int q = 0; q < 8; ++q) bcv[q] = *(const float4*)&lds_bc[0][q * 4];
    unsigned int cxr = *(const unsigned int*)&lds_x[0][d0];
    unsigned int cgr = *(const unsigned int*)&lds_g[0][d0];
    ushort8 xr0, xr1, gr0, gr1; float4 bc_r;
    for (int c = 0; c < 50; ++c) {
        int cur = c & 1;
        const size_t lbase = base + c * 8;
#pragma unroll
        for (int pp = 0; pp < 8; ++pp) {
            if (pp == 0 && c + 1 < 50) {
                size_t o = (lbase + 8) * 512 + t * 16;
                xr0 = *(const ushort8*)(xconv + o);
                xr1 = *(const ushort8*)(xconv + o + 8);
                gr0 = *(const ushort8*)(gres + o);
                gr1 = *(const ushort8*)(gres + o + 8);
                if (t < 64) bc_r = *(const float4*)(BC + (lbase + 8) * 32 + t * 4);
            }
            const f32x2* Bp = (const f32x2*)&bcv[0];
            const f32x2* Cp = (const f32x2*)&bcv[4];
            float x0 = b2f((unsigned short)(cxr & 0xffff)), x1 = b2f((unsigned short)(cxr >> 16));
            float ga0 = b2f((unsigned short)(cgr & 0xffff)), ga1 = b2f((unsigned short)(cgr >> 16));
            f32x2 o0A = (f32x2){x0 * Dd.x, 0.0f}, o0B = (f32x2)(0.0f);
            f32x2 o1A = (f32x2){x1 * Dd.y, 0.0f}, o1B = (f32x2)(0.0f);
#pragma unroll
            for (int j = 0; j < 8; j += 2) {
                st2[j]     = pk_add(st2[j],     Bp[j]);     o0A = pk_fma(st2[j],     Cp[j],     o0A);
                st2[j + 1] = pk_add(st2[j + 1], Bp[j + 1]); o0B = pk_fma(st2[j + 1], Cp[j + 1], o0B);
                st2[8 + j]     = pk_add(st2[8 + j],     Bp[j]);     o1A = pk_fma(st2[8 + j],     Cp[j],     o1A);
                st2[8 + j + 1] = pk_add(st2[8 + j + 1], Bp[j + 1]); o1B = pk_fma(st2[8 + j + 1], Cp[j + 1], o1B);
            }
            f32x2 o0 = pk_add(o0A, o0B), o1 = pk_add(o1A, o1B);
            unsigned int oy = (unsigned int)f2b((o0.x + o0.y) * ga0)
                            | ((unsigned int)f2b((o1.x + o1.y) * ga1) << 16);
            *(unsigned int*)(yg + (lbase + pp) * 512 + d0) = oy;
            f32x2 sA = (f32x2)(0.0f), sB = (f32x2)(0.0f), sC = (f32x2)(0.0f), sD = (f32x2)(0.0f);
            f32x2 qA = (f32x2)(0.0f), qB = (f32x2)(0.0f), qC = (f32x2)(0.0f), qD = (f32x2)(0.0f);
#pragma unroll
            for (int j = 0; j < 16; j += 4) {
                st2[j]     = pk_mul(st2[j],     tA2[j]);     sA = pk_add(sA, st2[j]);     qA = pk_fma(st2[j],     st2[j],     qA);
                st2[j + 1] = pk_mul(st2[j + 1], tA2[j + 1]); sB = pk_add(sB, st2[j + 1]); qB = pk_fma(st2[j + 1], st2[j + 1], qB);
                st2[j + 2] = pk_mul(st2[j + 2], tA2[j + 2]); sC = pk_add(sC, st2[j + 2]); qC = pk_fma(st2[j + 2], st2[j + 2], qC);
                st2[j + 3] = pk_mul(st2[j + 3], tA2[j + 3]); sD = pk_add(sD, st2[j + 3]); qD = pk_fma(st2[j + 3], st2[j + 3], qD);
            }
            f32x2 sS = pk_add(pk_add(sA, sB), pk_add(sC, sD));
            f32x2 qS = pk_add(pk_add(qA, qB), pk_add(qC, qD));
            float s1 = wave_sum63(sS.x + sS.y);
            float s2 = wave_sum63(qS.x + qS.y);
            if (pp == 6 && c + 1 < 50) {
                if (t < 64) *(float4*)(&lds_bc[cur ^ 1][t * 4]) = bc_r;
            }
            if (pp == 7 && c + 1 < 50) {
                *(ushort8*)(&lds_x[cur ^ 1][t * 16])     = xr0;
                *(ushort8*)(&lds_x[cur ^ 1][t * 16 + 8]) = xr1;
                *(ushort8*)(&lds_g[cur ^ 1][t * 16])     = gr0;
                *(ushort8*)(&lds_g[cur ^ 1][t * 16 + 8]) = gr1;
            }
            if ((t & 63) == 63) { lds_s1[pp & 1][t >> 6] = s1; lds_s2[pp & 1][t >> 6] = s2; }
            __builtin_amdgcn_sched_barrier(0);
            float4 nbc[8]; unsigned int nxr = 0, ngr = 0;
            if (pp < 7) {
#pragma unroll
                for (int q = 0; q < 8; ++q)
                    nbc[q] = *(const float4*)&lds_bc[cur][(pp + 1) * 32 + q * 4];
                nxr = *(const unsigned int*)&lds_x[cur][(pp + 1) * 512 + d0];
                ngr = *(const unsigned int*)&lds_g[cur][(pp + 1) * 512 + d0];
                __builtin_amdgcn_sched_barrier(0);
                asm volatile("s_waitcnt lgkmcnt(10)" ::: "memory");
            } else if (c + 1 < 50) {
#pragma unroll
                for (int q = 0; q < 8; ++q)
                    nbc[q] = *(const float4*)&lds_bc[cur ^ 1][q * 4];
                __builtin_amdgcn_sched_barrier(0);
                asm volatile("s_waitcnt lgkmcnt(8)" ::: "memory");
            } else {
                asm volatile("s_waitcnt lgkmcnt(0)" ::: "memory");
            }
            __builtin_amdgcn_s_barrier();
            __builtin_amdgcn_sched_barrier(0);
            float4 p0v = *(const float4*)&lds_s1[pp & 1][0];
            float4 r0v = *(const float4*)&lds_s2[pp & 1][0];
            float S1 = (p0v.x + p0v.y) + (p0v.z + p0v.w);
            float S2 = (r0v.x + r0v.y) + (r0v.z + r0v.w);
            float mu = S1 * (1.0f / 8192.0f);
            float var = S2 * (1.0f / 8192.0f) - mu * mu;
            float rs = rsqrtf(var + 1e-5f);
            f32x2 rs2 = (f32x2){rs, rs};
            f32x2 nm2 = (f32x2){-mu * rs, -mu * rs};
#pragma unroll
            for (int j = 0; j < 16; ++j) {
                f32x2 zn = pk_fma(st2[j], rs2, nm2);
                st2[j] = pk_fma(zn, g2[j], bb2[j]);
            }
            if (pp < 7) {
#pragma unroll
                for (int q = 0; q < 8; ++q) bcv[q] = nbc[q];
                cxr = nxr; cgr = ngr;
            } else if (c + 1 < 50) {
#pragma unroll
                for (int q = 0; q < 8; ++q) bcv[q] = nbc[q];
                cxr = *(const unsigned int*)&lds_x[cur ^ 1][d0];
                cgr = *(const unsigned int*)&lds_g[cur ^ 1][d0];
            }
        }
    }
}

// ---------------------------------------------------------------------------
// pooling stage A: partial sums over 50-position segments.
__global__ __launch_bounds__(256) void pool_partial_kernel(
    const float* __restrict__ h, float* __restrict__ part)
{
    int b = blockIdx.x >> 3, seg = blockIdx.x & 7;
    int t = threadIdx.x;
    const float* p = h + ((size_t)b * 400 + seg * 50) * 256 + t;
    float s = 0.0f;
#pragma unroll 5
    for (int l = 0; l < 50; ++l) s += p[(size_t)l * 256];
    part[((size_t)b * 8 + seg) * 256 + t] = s;
}

// pooling stage B: reduce 8 partials + FC (37 classes). 1 block per batch.
__global__ __launch_bounds__(256) void poolfc_kernel(
    const float* __restrict__ part, const float* __restrict__ fcw,
    const float* __restrict__ fcb, float* __restrict__ out)
{
    __shared__ float ps[256];
    int b = blockIdx.x, t = threadIdx.x;
    float s = 0.0f;
#pragma unroll
    for (int seg = 0; seg < 8; ++seg) s += part[((size_t)b * 8 + seg) * 256 + t];
    ps[t] = s * (1.0f / 400.0f);
    __syncthreads();
    if (t < 37) {
        float acc = fcb[t];
        for (int o = 0; o < 256; ++o) acc += ps[o] * fcw[t * 256 + o];
        out[b * 37 + t] = acc;
    }
}

// ---------------------------------------------------------------------------
extern "C" void kernel_launch(void* const* d_in, const int* in_sizes, int n_in,
                              void* d_out, int out_size, void* d_ws, size_t ws_size,
                              hipStream_t stream)
{
    const float* x         = (const float*)d_in[0];
    const float* conv1_w   = (const float*)d_in[1];
    const float* conv1_b   = (const float*)d_in[2];
    const float* conv2_w   = (const float*)d_in[3];
    const float* conv2_b   = (const float*)d_in[4];
    const float* ln_g      = (const float*)d_in[5];
    const float* ln_b      = (const float*)d_in[6];
    const float* inproj_w  = (const float*)d_in[7];
    const float* inproj_b  = (const float*)d_in[8];
    const float* dw_w      = (const float*)d_in[9];
    const float* dw_b      = (const float*)d_in[10];
    const float* xproj_w   = (const float*)d_in[11];
    const float* xproj_b   = (const float*)d_in[12];
    const float* A         = (const float*)d_in[13];
    const float* D         = (const float*)d_in[14];
    const float* sn_g      = (const float*)d_in[15];
    const float* sn_b      = (const float*)d_in[16];
    const float* outproj_w = (const float*)d_in[17];
    const float* outproj_b = (const float*)d_in[18];
    const float* fc_w      = (const float*)d_in[19];
    const float* fc_b      = (const float*)d_in[20];
    float* out = (float*)d_out;

    const int M = 51200; // B*L

    // Workspace: big buffers (243,007,488) + weights (2,031,616) + pool partials (1,048,576)
    if (ws_size < 245563392u) return;
    char* ws = (char*)d_ws;
    float*          h    = (float*)(ws);
    unsigned short* hn   = (unsigned short*)(ws + 52428800);
    unsigned short* h1   = (unsigned short*)(ws + 52428800);
    unsigned short* xp_c = (unsigned short*)(ws + 78643200);
    unsigned short* yg   = (unsigned short*)(ws + 78643200);
    unsigned short* grs  = (unsigned short*)(ws + 131072000);
    unsigned short* xcv  = (unsigned short*)(ws + 183500800);
    float*          BC   = (float*)(ws + 235929600);
    unsigned short* wb   = (unsigned short*)(ws + 242483200);
    unsigned short* w2r   = wb;
    unsigned short* winp0 = wb + 196608;
    unsigned short* winp1 = wb + 458752;
    unsigned short* wxp0  = wb + 720896;
    unsigned short* wxp1  = wb + 737280;
    unsigned short* wout0 = wb + 753664;
    unsigned short* wout1 = wb + 884736;
    float*          part  = (float*)(ws + 244514816);
    unsigned short* winp[2] = {winp0, winp1};
    unsigned short* wxp[2]  = {wxp0, wxp1};
    unsigned short* wout[2] = {wout0, wout1};

    // --- single fused weight-prep launch (fills entire wb area) ---
    prep_weights_kernel<<<3968, 256, 0, stream>>>(conv2_w, inproj_w, xproj_w, outproj_w, wb);

    conv1_kernel<<<128 * 8, 256, 0, stream>>>(x, conv1_w, conv1_b, h1);
    gemm_conv2<<<(M / 128) * 2, 256, 0, stream>>>(h1, w2r, conv2_b, h);

    for (int i = 0; i < 2; ++i) {
        ln_kernel<<<M / 4, 256, 0, stream>>>(h, ln_g + i * 256, ln_b + i * 256, hn);
        gemm_bt<4><<<(M / 128) * 8, 256, 0, stream>>>(hn, winp[i], inproj_b + i * 1024,
                                                      (const float*)grs, xp_c, 1024, 256, 256, 512);
        dwconv_kernel<<<2048, 256, 0, stream>>>(xp_c, dw_w + i * 1536, dw_b + i * 512, xcv);
        xproj_mfma<<<M / 128, 256, 0, stream>>>(xcv, wxp[i], xproj_b + i * 32, BC);
        scan_kernel<<<128, 256, 0, stream>>>(BC, xcv, grs, A + i * 8192, D + i * 512,
                                             sn_g + i * 8192, sn_b + i * 8192, yg);
        gemm_bt<3><<<(M / 128) * 2, 256, 0, stream>>>(yg, wout[i], outproj_b + i * 256, h, h,
                                                      256, 512, 512, 256);
    }
    pool_partial_kernel<<<128 * 8, 256, 0, stream>>>(h, part);
    poolfc_kernel<<<128, 256, 0, stream>>>(part, fc_w, fc_b, out);
}